// Round 13
// baseline (222.585 us; speedup 1.0000x reference)
//
#include <hip/hip_runtime.h>

#define N_NODES 40000
#define E_EDGES 640000
#define E_TOT   (E_EDGES + N_NODES)
#define SCAN_BLOCKS ((N_NODES + 255) / 256)   // 157
#define G1_BLOCKS 1250                        // 625 row-tiles x 2 col-panels
#define HIST_BLOCKS (E_EDGES / 256)           // 2500

typedef unsigned int uint;
typedef unsigned short ushort;

// bf16 helpers (RNE pack, cheap unpack)
__device__ __forceinline__ ushort f2bf(float f) {
    uint u = __float_as_uint(f);
    u += 0x7FFFu + ((u >> 16) & 1u);
    return (ushort)(u >> 16);
}
__device__ __forceinline__ uint pk_bf(float lo, float hi) {
    return (uint)f2bf(lo) | ((uint)f2bf(hi) << 16);
}
__device__ __forceinline__ float bf_lo(uint w) { return __uint_as_float(w << 16); }
__device__ __forceinline__ float bf_hi(uint w) { return __uint_as_float(w & 0xFFFF0000u); }

// ===========================================================================
// init_cnt: cnt[i] = 1 (self-loop baked in).
// ===========================================================================
__global__ __launch_bounds__(256) void init_cnt_kernel(int4* __restrict__ cnt4)
{
    const int i = blockIdx.x * 256 + threadIdx.x;
    if (i < 40064 / 4) cnt4[i] = make_int4(1, 1, 1, 1);
}

// ===========================================================================
// FUSED gemm1 ∥ hist (block-range partition, independent work, no coupling):
//   blocks [0, G1_BLOCKS)                -> 64x64 GEMM tile of h1 = x @ W1
//   blocks [G1_BLOCKS, G1_BLOCKS+2500)   -> edge histogram (1 edge/thread)
// hist's atomic latency hides in gemm1's idle issue slots.
// ===========================================================================
__global__ __launch_bounds__(256) void gemm1_hist_kernel(
    const float* __restrict__ x, const float* __restrict__ W,
    const float* __restrict__ a_src, const float* __restrict__ a_dst,
    ushort* __restrict__ h1b, float* __restrict__ asrc, float* __restrict__ adst,
    const int* __restrict__ eidx, int* __restrict__ cnt)
{
    __shared__ float Ws[128 * 64];   // 32 KB (hist blocks allocate, don't use)

    if (blockIdx.x >= G1_BLOCKS) {
        const int e = (blockIdx.x - G1_BLOCKS) * 256 + threadIdx.x;
        if (e < E_EDGES) atomicAdd(&cnt[eidx[E_EDGES + e]], 1);
        return;
    }

    const int cb = blockIdx.x & 1;
    const int row0 = (blockIdx.x >> 1) * 64;
    {
        const float4* Wg = (const float4*)W;
        float4* Wl = (float4*)Ws;
        for (int i = threadIdx.x; i < 128 * 64 / 4; i += 256) {
            const int r = i >> 4, c = i & 15;
            Wl[i] = Wg[r * 32 + cb * 16 + c];
        }
    }
    __syncthreads();
    const int tx = threadIdx.x & 15;
    const int ty = threadIdx.x >> 4;

    float acc[4][4];
#pragma unroll
    for (int r = 0; r < 4; ++r)
#pragma unroll
        for (int c = 0; c < 4; ++c) acc[r][c] = 0.f;

    for (int k0 = 0; k0 < 128; k0 += 4) {
        float xv[4][4];
#pragma unroll
        for (int r = 0; r < 4; ++r) {
            float4 t = *(const float4*)&x[(size_t)(row0 + ty * 4 + r) * 128 + k0];
            xv[r][0] = t.x; xv[r][1] = t.y; xv[r][2] = t.z; xv[r][3] = t.w;
        }
#pragma unroll
        for (int kk = 0; kk < 4; ++kk) {
            float4 w = *(const float4*)&Ws[(k0 + kk) * 64 + tx * 4];
            float wreg[4] = { w.x, w.y, w.z, w.w };
#pragma unroll
            for (int r = 0; r < 4; ++r)
#pragma unroll
                for (int c = 0; c < 4; ++c)
                    acc[r][c] = fmaf(xv[r][kk], wreg[c], acc[r][c]);
        }
    }

    const int head = 2 * cb + (tx >> 3);
    const int coff = (tx & 7) * 4;
    float as[4], ad[4];
#pragma unroll
    for (int c = 0; c < 4; ++c) {
        as[c] = a_src[head * 32 + coff + c];
        ad[c] = a_dst[head * 32 + coff + c];
    }
#pragma unroll
    for (int r = 0; r < 4; ++r) {
        const int n = row0 + ty * 4 + r;
        uint2 o;
        o.x = pk_bf(acc[r][0], acc[r][1]);
        o.y = pk_bf(acc[r][2], acc[r][3]);
        *(uint2*)&h1b[(size_t)n * 128 + cb * 64 + tx * 4] = o;
        float ps = 0.f, pd = 0.f;
#pragma unroll
        for (int c = 0; c < 4; ++c) {
            ps = fmaf(acc[r][c], as[c], ps);
            pd = fmaf(acc[r][c], ad[c], pd);
        }
        ps += __shfl_xor(ps, 1); ps += __shfl_xor(ps, 2); ps += __shfl_xor(ps, 4);
        pd += __shfl_xor(pd, 1); pd += __shfl_xor(pd, 2); pd += __shfl_xor(pd, 4);
        if ((tx & 7) == 0) {
            asrc[n * 4 + head] = ps;
            adst[n * 4 + head] = pd;
        }
    }
}

// ===========================================================================
// scanA/scanB/scanC: CSR prefix machinery.
// ===========================================================================
__global__ __launch_bounds__(256) void scanA_kernel(
    const int* __restrict__ cnt, int* __restrict__ rowptr, int* __restrict__ bsum)
{
    const int i = blockIdx.x * 256 + threadIdx.x;
    const int lane = threadIdx.x & 63;
    const int wave = threadIdx.x >> 6;
    const int v = (i < N_NODES) ? cnt[i] : 0;
    int incl = v;
#pragma unroll
    for (int off = 1; off < 64; off <<= 1) {
        int u = __shfl_up(incl, off);
        if (lane >= off) incl += u;
    }
    __shared__ int ws[4];
    if (lane == 63) ws[wave] = incl;
    __syncthreads();
    int woff = 0;
    if (wave > 0) woff += ws[0];
    if (wave > 1) woff += ws[1];
    if (wave > 2) woff += ws[2];
    if (i <= N_NODES) rowptr[i] = woff + incl - v;
    if (threadIdx.x == 255) bsum[blockIdx.x] = woff + incl;
}

__global__ __launch_bounds__(256) void scanB_kernel(int* __restrict__ bsum)
{
    const int t = threadIdx.x;
    const int lane = t & 63;
    const int wave = t >> 6;
    const int v = (t < SCAN_BLOCKS) ? bsum[t] : 0;
    int incl = v;
#pragma unroll
    for (int off = 1; off < 64; off <<= 1) {
        int u = __shfl_up(incl, off);
        if (lane >= off) incl += u;
    }
    __shared__ int ws[4];
    if (lane == 63) ws[wave] = incl;
    __syncthreads();
    int woff = 0;
    if (wave > 0) woff += ws[0];
    if (wave > 1) woff += ws[1];
    if (wave > 2) woff += ws[2];
    if (t < SCAN_BLOCKS) bsum[t] = woff + incl - v;
}

__global__ __launch_bounds__(256) void scanC_kernel(
    const int* __restrict__ rowptr, const int* __restrict__ bsum,
    int* __restrict__ rowfin, int* __restrict__ cursor)
{
    const int i = blockIdx.x * 256 + threadIdx.x;
    if (i > N_NODES) return;
    const int base = rowptr[i] + bsum[i >> 8];
    rowfin[i] = base;
    if (i < N_NODES) cursor[i] = base;
}

// fill: 1 edge/thread (max TLP), cursor atomic + scattered write.
__global__ __launch_bounds__(256) void fill_kernel(
    const int* __restrict__ eidx, int* __restrict__ cursor,
    int* __restrict__ esrc)
{
    const int e = blockIdx.x * 256 + threadIdx.x;
    if (e >= E_TOT) return;
    int s, d;
    if (e < E_EDGES) { s = eidx[e]; d = eidx[E_EDGES + e]; }
    else             { s = d = e - E_EDGES; }
    esrc[atomicAdd(&cursor[d], 1)] = s;
}

// ===========================================================================
// FUSED gather1 + gemm2, WAVE-LOCAL (no post-gather barrier):
// One barrier at entry to stage W2/a2 in LDS (uniform), then each wave:
//   Phase A: CSR gather -> agg row in registers (2 f32/lane, norm+bias+ELU)
//   Phase B: h2[n,:] = aggRow @ W2 via shfl-broadcast (no LDS round trip),
//            + layer-2 attention dots.
// ===========================================================================
__global__ __launch_bounds__(256) void gather1_gemm2_kernel(
    const int* __restrict__ rowfin,
    const int* __restrict__ esrc, const float* __restrict__ asrc,
    const float* __restrict__ adst,
    const ushort* __restrict__ h1b, const float* __restrict__ b,
    const float* __restrict__ W2,
    const float* __restrict__ a_src2, const float* __restrict__ a_dst2,
    float* __restrict__ h2, float* __restrict__ asrc2, float* __restrict__ adst2)
{
    __shared__ float Ws2[128 * 32];   // 16 KB
    __shared__ float asv[32], adv[32];
    {
        const float4* Wg = (const float4*)W2;
        float4* Wl = (float4*)Ws2;
        for (int i = threadIdx.x; i < 128 * 32 / 4; i += 256) Wl[i] = Wg[i];
        if (threadIdx.x < 32) {
            asv[threadIdx.x] = a_src2[threadIdx.x];
            adv[threadIdx.x] = a_dst2[threadIdx.x];
        }
    }
    __syncthreads();   // uniform staging barrier only — waves now independent

    const int wv = threadIdx.x >> 6;
    const int lane = threadIdx.x & 63;
    const int node = blockIdx.x * 4 + wv;   // grid exact: 10000*4 = 40000
    const int head = lane >> 4;
    const float ad = adst[node * 4 + head];
    const int beg = rowfin[node], end = rowfin[node + 1];
    float acc0 = 0.f, acc1 = 0.f, den = 0.f;

    int i = beg;
    for (; i + 8 <= end; i += 8) {
        int s[8];
        float a[8];
        uint w[8];
#pragma unroll
        for (int j = 0; j < 8; ++j) s[j] = esrc[i + j];
#pragma unroll
        for (int j = 0; j < 8; ++j) a[j] = asrc[s[j] * 4 + head];
#pragma unroll
        for (int j = 0; j < 8; ++j)
            w[j] = *(const uint*)&h1b[(size_t)s[j] * 128 + lane * 2];
#pragma unroll
        for (int j = 0; j < 8; ++j) {
            float v = a[j] + ad; v = v > 0.f ? v : 0.2f * v;
            const float e = __expf(v);
            den += e;
            acc0 = fmaf(e, bf_lo(w[j]), acc0);
            acc1 = fmaf(e, bf_hi(w[j]), acc1);
        }
    }
    for (; i < end; ++i) {
        const int s = esrc[i];
        float av = asrc[s * 4 + head] + ad;
        av = av > 0.f ? av : 0.2f * av;
        const float ex = __expf(av);
        const uint w = *(const uint*)&h1b[(size_t)s * 128 + lane * 2];
        den += ex;
        acc0 = fmaf(ex, bf_lo(w), acc0);
        acc1 = fmaf(ex, bf_hi(w), acc1);
    }

    const float inv = 1.f / (den + 1e-16f);
    const float2 bv = *(const float2*)&b[lane * 2];
    float o0 = acc0 * inv + bv.x;   // agg channel 2*lane
    float o1 = acc1 * inv + bv.y;   // agg channel 2*lane+1
    o0 = o0 > 0.f ? o0 : expm1f(o0);
    o1 = o1 > 0.f ? o1 : expm1f(o1);

    // ---- Phase B (wave-local): h2 row = aggRow @ W2 ----
    // half h covers k in [h*64, h*64+64); lane c = lane&31 owns output col c.
    const int half = lane >> 5;
    const int c = lane & 31;
    float v = 0.f;
#pragma unroll
    for (int j = 0; j < 32; ++j) {
        const int src = half * 32 + j;       // source lane holding k=2*src,2*src+1
        const float a0 = __shfl(o0, src);
        const float a1 = __shfl(o1, src);
        v = fmaf(a0, Ws2[(2 * src) * 32 + c], v);
        v = fmaf(a1, Ws2[(2 * src + 1) * 32 + c], v);
    }
    v += __shfl_xor(v, 32);                  // combine halves: full dot in all lanes
    float ps = v * asv[c];
    float pd = v * adv[c];
    ps += __shfl_xor(ps, 1); ps += __shfl_xor(ps, 2); ps += __shfl_xor(ps, 4);
    ps += __shfl_xor(ps, 8); ps += __shfl_xor(ps, 16);
    pd += __shfl_xor(pd, 1); pd += __shfl_xor(pd, 2); pd += __shfl_xor(pd, 4);
    pd += __shfl_xor(pd, 8); pd += __shfl_xor(pd, 16);
    if (lane < 32) h2[(size_t)node * 32 + c] = v;
    if (lane == 0) { asrc2[node] = ps; adst2[node] = pd; }
}

// ===========================================================================
// FUSED gather2 + out_gemm, WAVE-LOCAL (no post-gather barrier):
// Each wave handles 2 nodes (32 lanes each). One entry barrier stages W_out.
//   Phase A: gather -> agg2 value per lane (1 f32, norm+bias+ELU)
//   Phase B: out[n,:] = agg2Row @ W_out + b_out via shfl-broadcast.
// ===========================================================================
__global__ __launch_bounds__(256) void gather2_out_kernel(
    const int* __restrict__ rowfin,
    const int* __restrict__ esrc,
    const float* __restrict__ asrc, const float* __restrict__ adst,
    const float* __restrict__ h2, const float* __restrict__ b,
    const float* __restrict__ W_out, const float* __restrict__ b_out,
    float* __restrict__ out)
{
    __shared__ float Wo[32 * 112];   // 14 KB
    __shared__ float boL[112];
    {
        const float4* Wg = (const float4*)W_out;
        float4* Wl = (float4*)Wo;
        for (int i = threadIdx.x; i < 32 * 112 / 4; i += 256) Wl[i] = Wg[i];
        if (threadIdx.x < 112) boL[threadIdx.x] = b_out[threadIdx.x];
    }
    __syncthreads();   // uniform staging barrier only

    const int wv = threadIdx.x >> 6;
    const int lane = threadIdx.x & 63;
    const int grp = lane >> 5;               // 0 or 1: which node in the wave
    const int c = lane & 31;
    const int node = blockIdx.x * 8 + wv * 2 + grp;  // grid exact: 5000*8
    const float ad = adst[node];
    const int beg = rowfin[node], end = rowfin[node + 1];
    float acc = 0.f, den = 0.f;

    int i = beg;
    for (; i + 8 <= end; i += 8) {
        int s[8];
        float a[8], h[8];
#pragma unroll
        for (int j = 0; j < 8; ++j) s[j] = esrc[i + j];
#pragma unroll
        for (int j = 0; j < 8; ++j) a[j] = asrc[s[j]];
#pragma unroll
        for (int j = 0; j < 8; ++j) h[j] = h2[(size_t)s[j] * 32 + c];
#pragma unroll
        for (int j = 0; j < 8; ++j) {
            float v = a[j] + ad; v = v > 0.f ? v : 0.2f * v;
            const float e = __expf(v);
            den += e;
            acc = fmaf(e, h[j], acc);
        }
    }
    for (; i < end; ++i) {
        const int s = esrc[i];
        float av = asrc[s] + ad;
        av = av > 0.f ? av : 0.2f * av;
        const float ex = __expf(av);
        den += ex;
        acc = fmaf(ex, h2[(size_t)s * 32 + c], acc);
    }

    const float inv = 1.f / (den + 1e-16f);
    float o = acc * inv + b[c];              // agg2 channel c of this node
    o = o > 0.f ? o : expm1f(o);

    // ---- Phase B (wave-local): out row = agg2Row @ W_out + b_out ----
    // Lane owns cols c, c+32, c+64, (c+96 if c<16). Broadcast k within group.
    float v0 = boL[c], v1 = boL[c + 32], v2 = boL[c + 64];
    float v3 = (c < 16) ? boL[c + 96] : 0.f;
    const int gbase = grp << 5;
#pragma unroll
    for (int k = 0; k < 32; ++k) {
        const float a = __shfl(o, gbase + k);
        v0 = fmaf(a, Wo[k * 112 + c], v0);
        v1 = fmaf(a, Wo[k * 112 + c + 32], v1);
        v2 = fmaf(a, Wo[k * 112 + c + 64], v2);
        if (c < 16) v3 = fmaf(a, Wo[k * 112 + c + 96], v3);
    }
    float* orow = &out[(size_t)node * 112];
    orow[c] = v0;
    orow[c + 32] = v1;
    orow[c + 64] = v2;
    if (c < 16) orow[c + 96] = v3;
}

// ===========================================================================
extern "C" void kernel_launch(void* const* d_in, const int* in_sizes, int n_in,
                              void* d_out, int out_size, void* d_ws, size_t ws_size,
                              hipStream_t stream) {
    const float* x      = (const float*)d_in[0];
    const int*   eidx   = (const int*)d_in[1];
    const float* W1     = (const float*)d_in[2];
    const float* a_src1 = (const float*)d_in[3];
    const float* a_dst1 = (const float*)d_in[4];
    const float* b1     = (const float*)d_in[5];
    const float* W2     = (const float*)d_in[6];
    const float* a_src2 = (const float*)d_in[7];
    const float* a_dst2 = (const float*)d_in[8];
    const float* b2     = (const float*)d_in[9];
    const float* W_out  = (const float*)d_in[10];
    const float* b_out  = (const float*)d_in[11];
    float* out = (float*)d_out;

    // ---- workspace layout (~20 MB) ----
    int* rowptr = (int*)d_ws;                 // 40064
    int* rowfin = rowptr + 40064;             // 40064
    int* cnt    = rowfin + 40064;             // 40064
    int* cursor = cnt + 40064;                // 40064
    int* bsum   = cursor + 40064;             // 256
    int* esrc   = bsum + 256;                 // 680000
    ushort* h1b  = (ushort*)(esrc + 680000);  // 40000*128 bf16
    float* asrc1 = (float*)(h1b + 5120000);   // 40000*4
    float* adst1 = asrc1 + 160000;            // 40000*4
    float* h2    = adst1 + 160000;            // 40000*32
    float* asrc2 = h2 + 1280000;              // 40000
    float* adst2 = asrc2 + 40000;             // 40000

    // CSR counter init (must precede the fused kernel's hist partition)
    init_cnt_kernel<<<(40064 / 4 + 255) / 256, 256, 0, stream>>>((int4*)cnt);

    // Layer-1 GEMM ∥ edge histogram (independent block partitions)
    gemm1_hist_kernel<<<G1_BLOCKS + HIST_BLOCKS, 256, 0, stream>>>(
        x, W1, a_src1, a_dst1, h1b, asrc1, adst1, eidx, cnt);

    // CSR scan + bucket fill
    scanA_kernel<<<SCAN_BLOCKS, 256, 0, stream>>>(cnt, rowptr, bsum);
    scanB_kernel<<<1, 256, 0, stream>>>(bsum);
    scanC_kernel<<<SCAN_BLOCKS, 256, 0, stream>>>(rowptr, bsum, rowfin, cursor);
    fill_kernel<<<(E_TOT + 255) / 256, 256, 0, stream>>>(eidx, cursor, esrc);

    // Layer-1 aggregate + Layer-2 GEMM (wave-local fusion)
    gather1_gemm2_kernel<<<10000, 256, 0, stream>>>(
        rowfin, esrc, asrc1, adst1, h1b, b1, W2, a_src2, a_dst2,
        h2, asrc2, adst2);

    // Layer-2 aggregate + output projection (wave-local fusion)
    gather2_out_kernel<<<5000, 256, 0, stream>>>(
        rowfin, esrc, asrc2, adst2, h2, b2, W_out, b_out, out);
}

// Round 14
// 169.139 us; speedup vs baseline: 1.3160x; 1.3160x over previous
//
#include <hip/hip_runtime.h>

#define N_NODES 40000
#define E_EDGES 640000
#define E_TOT   (E_EDGES + N_NODES)
#define SCAN_BLOCKS ((N_NODES + 255) / 256)   // 157
#define G1_BLOCKS 2500                        // 625 row-tiles x 4 col-panels

typedef unsigned int uint;
typedef unsigned short ushort;

// bf16 helpers (RNE pack, cheap unpack)
__device__ __forceinline__ ushort f2bf(float f) {
    uint u = __float_as_uint(f);
    u += 0x7FFFu + ((u >> 16) & 1u);
    return (ushort)(u >> 16);
}
__device__ __forceinline__ uint pk_bf(float lo, float hi) {
    return (uint)f2bf(lo) | ((uint)f2bf(hi) << 16);
}
__device__ __forceinline__ float bf_lo(uint w) { return __uint_as_float(w << 16); }
__device__ __forceinline__ float bf_hi(uint w) { return __uint_as_float(w & 0xFFFF0000u); }

// ===========================================================================
// init_cnt: cnt[i] = 1 (self-loop contribution baked in; the hist tail in
// gemm1 covers only the 640k real edges).
// ===========================================================================
__global__ __launch_bounds__(256) void init_cnt_kernel(int4* __restrict__ cnt4)
{
    const int i = blockIdx.x * 256 + threadIdx.x;
    if (i < 40064 / 4) cnt4[i] = make_int4(1, 1, 1, 1);
}

// ===========================================================================
// GEMM1: h1 = x @ W1 [40000x128 @ 128x128]; h1 bf16; fused attention coeffs;
// fused histogram tail (exactly 1 edge per thread: 2500*256 == 640000).
// Tile: 64 rows x 32 cols (gemm2's shape): 16 KB LDS -> ~2x block residency
// vs the 64x64/32KB shape (R8: occupancy 26%, latency-bound).
// blockIdx = row_tile*4 + col_panel; col panel == head.
// ===========================================================================
__global__ __launch_bounds__(256) void gemm1_kernel(
    const float* __restrict__ x, const float* __restrict__ W,
    const float* __restrict__ a_src, const float* __restrict__ a_dst,
    ushort* __restrict__ h1b, float* __restrict__ asrc, float* __restrict__ adst,
    const int* __restrict__ eidx, int* __restrict__ cnt)
{
    __shared__ float Ws[128 * 32];   // 16 KB
    const int cb = blockIdx.x & 3;        // column panel = head (cols cb*32..+31)
    const int row0 = (blockIdx.x >> 2) * 64;
    {
        const float4* Wg = (const float4*)W;
        float4* Wl = (float4*)Ws;
        for (int i = threadIdx.x; i < 128 * 32 / 4; i += 256) {
            const int r = i >> 3, c = i & 7;        // 8 float4 per LDS row
            Wl[i] = Wg[r * 32 + cb * 8 + c];
        }
    }
    __syncthreads();
    const int tx = threadIdx.x & 7;    // 8 col-groups of 4 cols
    const int ty = threadIdx.x >> 3;   // 32 row-groups of 2 rows

    float acc[2][4];
#pragma unroll
    for (int r = 0; r < 2; ++r)
#pragma unroll
        for (int c = 0; c < 4; ++c) acc[r][c] = 0.f;

    for (int k0 = 0; k0 < 128; k0 += 4) {
        float xv[2][4];
#pragma unroll
        for (int r = 0; r < 2; ++r) {
            float4 t = *(const float4*)&x[(size_t)(row0 + ty * 2 + r) * 128 + k0];
            xv[r][0] = t.x; xv[r][1] = t.y; xv[r][2] = t.z; xv[r][3] = t.w;
        }
#pragma unroll
        for (int kk = 0; kk < 4; ++kk) {
            float4 w = *(const float4*)&Ws[(k0 + kk) * 32 + tx * 4];
            float wreg[4] = { w.x, w.y, w.z, w.w };
#pragma unroll
            for (int r = 0; r < 2; ++r)
#pragma unroll
                for (int c = 0; c < 4; ++c)
                    acc[r][c] = fmaf(xv[r][kk], wreg[c], acc[r][c]);
        }
    }

    // cols cb*32 + tx*4 + c  ->  head = cb, within-head offset tx*4 + c.
    const int coff = tx * 4;
    float as[4], ad[4];
#pragma unroll
    for (int c = 0; c < 4; ++c) {
        as[c] = a_src[cb * 32 + coff + c];
        ad[c] = a_dst[cb * 32 + coff + c];
    }
#pragma unroll
    for (int r = 0; r < 2; ++r) {
        const int n = row0 + ty * 2 + r;
        uint2 o;
        o.x = pk_bf(acc[r][0], acc[r][1]);
        o.y = pk_bf(acc[r][2], acc[r][3]);
        *(uint2*)&h1b[(size_t)n * 128 + cb * 32 + tx * 4] = o;
        float ps = 0.f, pd = 0.f;
#pragma unroll
        for (int c = 0; c < 4; ++c) {
            ps = fmaf(acc[r][c], as[c], ps);
            pd = fmaf(acc[r][c], ad[c], pd);
        }
        ps += __shfl_xor(ps, 1); ps += __shfl_xor(ps, 2); ps += __shfl_xor(ps, 4);
        pd += __shfl_xor(pd, 1); pd += __shfl_xor(pd, 2); pd += __shfl_xor(pd, 4);
        if ((threadIdx.x & 7) == 0) {
            asrc[n * 4 + cb] = ps;
            adst[n * 4 + cb] = pd;
        }
    }

    // ---- fused histogram tail: exactly one real edge per thread ----
    const int e = blockIdx.x * 256 + threadIdx.x;   // [0, 640000)
    atomicAdd(&cnt[eidx[E_EDGES + e]], 1);
}

// ===========================================================================
// scanA: block-local exclusive scan (incl. boundary slot); block total ->
// bsum; zeroes the fill cursor.
// ===========================================================================
__global__ __launch_bounds__(256) void scanA_kernel(
    const int* __restrict__ cnt, int* __restrict__ rowptr, int* __restrict__ bsum,
    int* __restrict__ cursor)
{
    const int i = blockIdx.x * 256 + threadIdx.x;
    const int lane = threadIdx.x & 63;
    const int wave = threadIdx.x >> 6;
    const int v = (i < N_NODES) ? cnt[i] : 0;
    int incl = v;
#pragma unroll
    for (int off = 1; off < 64; off <<= 1) {
        int u = __shfl_up(incl, off);
        if (lane >= off) incl += u;
    }
    __shared__ int ws[4];
    if (lane == 63) ws[wave] = incl;
    __syncthreads();
    int woff = 0;
    if (wave > 0) woff += ws[0];
    if (wave > 1) woff += ws[1];
    if (wave > 2) woff += ws[2];
    if (i <= N_NODES) rowptr[i] = woff + incl - v;   // block-local exclusive
    if (i < N_NODES) cursor[i] = 0;
    if (threadIdx.x == 255) bsum[blockIdx.x] = woff + incl;
}

// Single block: exclusive scan of the 157 block sums in place.
__global__ __launch_bounds__(256) void scanB_kernel(int* __restrict__ bsum)
{
    const int t = threadIdx.x;
    const int lane = t & 63;
    const int wave = t >> 6;
    const int v = (t < SCAN_BLOCKS) ? bsum[t] : 0;
    int incl = v;
#pragma unroll
    for (int off = 1; off < 64; off <<= 1) {
        int u = __shfl_up(incl, off);
        if (lane >= off) incl += u;
    }
    __shared__ int ws[4];
    if (lane == 63) ws[wave] = incl;
    __syncthreads();
    int woff = 0;
    if (wave > 0) woff += ws[0];
    if (wave > 1) woff += ws[1];
    if (wave > 2) woff += ws[2];
    if (t < SCAN_BLOCKS) bsum[t] = woff + incl - v;  // exclusive
}

// Bucket edges by dst (1 edge/thread, max TLP).
__global__ __launch_bounds__(256) void fill_kernel(
    const int* __restrict__ eidx, const int* __restrict__ rowptr,
    const int* __restrict__ bsum, int* __restrict__ cursor,
    int* __restrict__ esrc)
{
    const int e = blockIdx.x * 256 + threadIdx.x;
    if (e >= E_TOT) return;
    int s, d;
    if (e < E_EDGES) { s = eidx[e]; d = eidx[E_EDGES + e]; }
    else             { s = d = e - E_EDGES; }
    const int pos = atomicAdd(&cursor[d], 1);
    esrc[rowptr[d] + bsum[d >> 8] + pos] = s;
}

// ===========================================================================
// Gather pass 1: one wave per dst node; bf16 rows; 8-deep pipeline;
// fused normalize + bias + ELU.
// ===========================================================================
__global__ __launch_bounds__(256) void gather1_kernel(
    const int* __restrict__ rowptr, const int* __restrict__ bsum,
    const int* __restrict__ esrc, const float* __restrict__ asrc,
    const float* __restrict__ adst,
    const ushort* __restrict__ h1b, const float* __restrict__ b,
    float* __restrict__ agg)
{
    const int node = (blockIdx.x * 256 + threadIdx.x) >> 6;
    const int lane = threadIdx.x & 63;
    if (node >= N_NODES) return;
    const int head = lane >> 4;
    const float ad = adst[node * 4 + head];
    const int beg = rowptr[node] + bsum[node >> 8];
    const int end = rowptr[node + 1] + bsum[(node + 1) >> 8];
    float acc0 = 0.f, acc1 = 0.f, den = 0.f;

    int i = beg;
    for (; i + 8 <= end; i += 8) {
        int s[8];
        float a[8];
        uint w[8];
#pragma unroll
        for (int j = 0; j < 8; ++j) s[j] = esrc[i + j];
#pragma unroll
        for (int j = 0; j < 8; ++j) a[j] = asrc[s[j] * 4 + head];
#pragma unroll
        for (int j = 0; j < 8; ++j)
            w[j] = *(const uint*)&h1b[(size_t)s[j] * 128 + lane * 2];
#pragma unroll
        for (int j = 0; j < 8; ++j) {
            float v = a[j] + ad; v = v > 0.f ? v : 0.2f * v;
            const float e = __expf(v);
            den += e;
            acc0 = fmaf(e, bf_lo(w[j]), acc0);
            acc1 = fmaf(e, bf_hi(w[j]), acc1);
        }
    }
    for (; i < end; ++i) {
        const int s = esrc[i];
        float av = asrc[s * 4 + head] + ad;
        av = av > 0.f ? av : 0.2f * av;
        const float ex = __expf(av);
        const uint w = *(const uint*)&h1b[(size_t)s * 128 + lane * 2];
        den += ex;
        acc0 = fmaf(ex, bf_lo(w), acc0);
        acc1 = fmaf(ex, bf_hi(w), acc1);
    }

    const float inv = 1.f / (den + 1e-16f);
    const float2 bv = *(const float2*)&b[lane * 2];
    float o0 = acc0 * inv + bv.x;
    float o1 = acc1 * inv + bv.y;
    o0 = o0 > 0.f ? o0 : expm1f(o0);
    o1 = o1 > 0.f ? o1 : expm1f(o1);
    *(float2*)&agg[(size_t)node * 128 + lane * 2] = make_float2(o0, o1);
}

// ===========================================================================
// GEMM2: h2 = hin @ W2  [40000x128 @ 128x32], fused attention coeffs (1 head)
// ===========================================================================
__global__ __launch_bounds__(256) void gemm2_kernel(
    const float* __restrict__ hin, const float* __restrict__ W,
    const float* __restrict__ a_src, const float* __restrict__ a_dst,
    float* __restrict__ h2, float* __restrict__ asrc, float* __restrict__ adst)
{
    __shared__ float Ws[128 * 32];   // 16 KB
    {
        const float4* Wg = (const float4*)W;
        float4* Wl = (float4*)Ws;
        for (int i = threadIdx.x; i < 128 * 32 / 4; i += 256) Wl[i] = Wg[i];
    }
    __syncthreads();
    const int row0 = blockIdx.x * 64;
    const int tx = threadIdx.x & 7;
    const int ty = threadIdx.x >> 3;

    float acc[2][4];
#pragma unroll
    for (int r = 0; r < 2; ++r)
#pragma unroll
        for (int c = 0; c < 4; ++c) acc[r][c] = 0.f;

    for (int k0 = 0; k0 < 128; k0 += 4) {
        float xv[2][4];
#pragma unroll
        for (int r = 0; r < 2; ++r) {
            float4 t = *(const float4*)&hin[(size_t)(row0 + ty * 2 + r) * 128 + k0];
            xv[r][0] = t.x; xv[r][1] = t.y; xv[r][2] = t.z; xv[r][3] = t.w;
        }
#pragma unroll
        for (int kk = 0; kk < 4; ++kk) {
            float4 w = *(const float4*)&Ws[(k0 + kk) * 32 + tx * 4];
            float wreg[4] = { w.x, w.y, w.z, w.w };
#pragma unroll
            for (int r = 0; r < 2; ++r)
#pragma unroll
                for (int c = 0; c < 4; ++c)
                    acc[r][c] = fmaf(xv[r][kk], wreg[c], acc[r][c]);
        }
    }

    float as[4], ad[4];
#pragma unroll
    for (int c = 0; c < 4; ++c) {
        as[c] = a_src[tx * 4 + c];
        ad[c] = a_dst[tx * 4 + c];
    }
#pragma unroll
    for (int r = 0; r < 2; ++r) {
        const int n = row0 + ty * 2 + r;
        *(float4*)&h2[(size_t)n * 32 + tx * 4] =
            make_float4(acc[r][0], acc[r][1], acc[r][2], acc[r][3]);
        float ps = 0.f, pd = 0.f;
#pragma unroll
        for (int c = 0; c < 4; ++c) {
            ps = fmaf(acc[r][c], as[c], ps);
            pd = fmaf(acc[r][c], ad[c], pd);
        }
        ps += __shfl_xor(ps, 1); ps += __shfl_xor(ps, 2); ps += __shfl_xor(ps, 4);
        pd += __shfl_xor(pd, 1); pd += __shfl_xor(pd, 2); pd += __shfl_xor(pd, 4);
        if ((threadIdx.x & 7) == 0) { asrc[n] = ps; adst[n] = pd; }
    }
}

// ===========================================================================
// Gather pass 2: 32 lanes per dst node, 8-deep pipeline; fused norm+bias+ELU.
// ===========================================================================
__global__ __launch_bounds__(256) void gather2_kernel(
    const int* __restrict__ rowptr, const int* __restrict__ bsum,
    const int* __restrict__ esrc,
    const float* __restrict__ asrc, const float* __restrict__ adst,
    const float* __restrict__ h2, const float* __restrict__ b,
    float* __restrict__ agg)
{
    const int t = blockIdx.x * 256 + threadIdx.x;
    const int node = t >> 5;
    const int c = t & 31;
    if (node >= N_NODES) return;
    const float ad = adst[node];
    const int beg = rowptr[node] + bsum[node >> 8];
    const int end = rowptr[node + 1] + bsum[(node + 1) >> 8];
    float acc = 0.f, den = 0.f;

    int i = beg;
    for (; i + 8 <= end; i += 8) {
        int s[8];
        float a[8], h[8];
#pragma unroll
        for (int j = 0; j < 8; ++j) s[j] = esrc[i + j];
#pragma unroll
        for (int j = 0; j < 8; ++j) a[j] = asrc[s[j]];
#pragma unroll
        for (int j = 0; j < 8; ++j) h[j] = h2[(size_t)s[j] * 32 + c];
#pragma unroll
        for (int j = 0; j < 8; ++j) {
            float v = a[j] + ad; v = v > 0.f ? v : 0.2f * v;
            const float e = __expf(v);
            den += e;
            acc = fmaf(e, h[j], acc);
        }
    }
    for (; i < end; ++i) {
        const int s = esrc[i];
        float av = asrc[s] + ad;
        av = av > 0.f ? av : 0.2f * av;
        const float ex = __expf(av);
        den += ex;
        acc = fmaf(ex, h2[(size_t)s * 32 + c], acc);
    }

    const float inv = 1.f / (den + 1e-16f);
    float o = acc * inv + b[c];
    o = o > 0.f ? o : expm1f(o);
    agg[(size_t)node * 32 + c] = o;
}

// ===========================================================================
// Output GEMM: out = h3 @ W_out + b_out  [40000x32 @ 32x112]
// ===========================================================================
__global__ __launch_bounds__(256) void out_gemm_kernel(
    const float* __restrict__ h3, const float* __restrict__ W,
    const float* __restrict__ b, float* __restrict__ out)
{
    __shared__ float Ws[32 * 112];   // 14 KB
    {
        const float4* Wg = (const float4*)W;
        float4* Wl = (float4*)Ws;
        for (int i = threadIdx.x; i < 32 * 112 / 4; i += 256) Wl[i] = Wg[i];
    }
    __syncthreads();
    const int row0 = blockIdx.x * 32;
    const int tc = threadIdx.x & 15;
    const int tr = threadIdx.x >> 4;

    float acc[2][7];
#pragma unroll
    for (int r = 0; r < 2; ++r)
#pragma unroll
        for (int c = 0; c < 7; ++c) acc[r][c] = 0.f;

    for (int k0 = 0; k0 < 32; k0 += 4) {
        float xv[2][4];
#pragma unroll
        for (int r = 0; r < 2; ++r) {
            float4 t = *(const float4*)&h3[(size_t)(row0 + tr * 2 + r) * 32 + k0];
            xv[r][0] = t.x; xv[r][1] = t.y; xv[r][2] = t.z; xv[r][3] = t.w;
        }
#pragma unroll
        for (int kk = 0; kk < 4; ++kk) {
            float wv[7];
#pragma unroll
            for (int c = 0; c < 7; ++c) wv[c] = Ws[(k0 + kk) * 112 + tc * 7 + c];
#pragma unroll
            for (int r = 0; r < 2; ++r)
#pragma unroll
                for (int c = 0; c < 7; ++c)
                    acc[r][c] = fmaf(xv[r][kk], wv[c], acc[r][c]);
        }
    }
#pragma unroll
    for (int r = 0; r < 2; ++r) {
        const int n = row0 + tr * 2 + r;
#pragma unroll
        for (int c = 0; c < 7; ++c)
            out[(size_t)n * 112 + tc * 7 + c] = acc[r][c] + b[tc * 7 + c];
    }
}

// ===========================================================================
extern "C" void kernel_launch(void* const* d_in, const int* in_sizes, int n_in,
                              void* d_out, int out_size, void* d_ws, size_t ws_size,
                              hipStream_t stream) {
    const float* x      = (const float*)d_in[0];
    const int*   eidx   = (const int*)d_in[1];
    const float* W1     = (const float*)d_in[2];
    const float* a_src1 = (const float*)d_in[3];
    const float* a_dst1 = (const float*)d_in[4];
    const float* b1     = (const float*)d_in[5];
    const float* W2     = (const float*)d_in[6];
    const float* a_src2 = (const float*)d_in[7];
    const float* a_dst2 = (const float*)d_in[8];
    const float* b2     = (const float*)d_in[9];
    const float* W_out  = (const float*)d_in[10];
    const float* b_out  = (const float*)d_in[11];
    float* out = (float*)d_out;

    // ---- workspace layout (~35 MB) ----
    int* rowptr = (int*)d_ws;                 // 40064 (uses [0..40000])
    int* cnt    = rowptr + 40064;             // 40064 histogram
    int* cursor = cnt + 40064;                // 40064 fill cursor
    int* bsum   = cursor + 40064;             // 192 block sums (exclusive)
    int* esrc   = bsum + 192;                 // 680000 CSR edge sources
    ushort* h1b  = (ushort*)(esrc + 680000);  // 40000*128 bf16
    float* asrc1 = (float*)(h1b + 5120000);   // 40000*4
    float* adst1 = asrc1 + 160000;            // 40000*4
    float* agg1  = adst1 + 160000;            // 40000*128
    // after gather1, h1b region is dead -> layer-2 buffers overlay it
    float* h2    = (float*)h1b;               // 40000*32
    float* asrc2 = h2 + 1280000;              // 40000
    float* adst2 = asrc2 + 40000;             // 40000
    float* agg2  = adst2 + 40000;             // 40000*32

    // cnt = 1 everywhere (self-loops baked) before gemm1's histogram tail
    init_cnt_kernel<<<(40064 / 4 + 255) / 256, 256, 0, stream>>>((int4*)cnt);

    // Layer-1 GEMM + fused edge histogram (1 edge/thread exactly)
    gemm1_kernel<<<G1_BLOCKS, 256, 0, stream>>>(x, W1, a_src1, a_dst1, h1b,
                                                asrc1, adst1, eidx, cnt);
    // CSR build (shared by both layers)
    scanA_kernel<<<SCAN_BLOCKS, 256, 0, stream>>>(cnt, rowptr, bsum, cursor);
    scanB_kernel<<<1, 256, 0, stream>>>(bsum);
    fill_kernel<<<(E_TOT + 255) / 256, 256, 0, stream>>>(
        eidx, rowptr, bsum, cursor, esrc);

    // Layer 1 aggregate
    gather1_kernel<<<10000, 256, 0, stream>>>(rowptr, bsum, esrc, asrc1, adst1,
                                              h1b, b1, agg1);

    // Layer 2
    gemm2_kernel<<<625, 256, 0, stream>>>(agg1, W2, a_src2, a_dst2, h2, asrc2, adst2);
    gather2_kernel<<<5000, 256, 0, stream>>>(rowptr, bsum, esrc, asrc2, adst2,
                                             h2, b2, agg2);

    // Output projection
    out_gemm_kernel<<<1250, 256, 0, stream>>>(agg2, W_out, b_out, out);
}

// Round 15
// 163.078 us; speedup vs baseline: 1.3649x; 1.0372x over previous
//
#include <hip/hip_runtime.h>

#define N_NODES 40000
#define E_EDGES 640000
#define E_TOT   (E_EDGES + N_NODES)
#define SCAN_BLOCKS ((N_NODES + 255) / 256)   // 157
#define G1_BLOCKS 625                         // 64 rows per block (4 waves x 16)

typedef unsigned int uint;
typedef unsigned short ushort;
typedef __attribute__((ext_vector_type(8))) short short8v;   // 8 bf16 (4 VGPRs)
typedef __attribute__((ext_vector_type(4))) float f32x4;     // MFMA accumulator

// bf16 helpers (RNE pack, cheap unpack)
__device__ __forceinline__ ushort f2bf(float f) {
    uint u = __float_as_uint(f);
    u += 0x7FFFu + ((u >> 16) & 1u);
    return (ushort)(u >> 16);
}
__device__ __forceinline__ uint pk_bf(float lo, float hi) {
    return (uint)f2bf(lo) | ((uint)f2bf(hi) << 16);
}
__device__ __forceinline__ float bf_lo(uint w) { return __uint_as_float(w << 16); }
__device__ __forceinline__ float bf_hi(uint w) { return __uint_as_float(w & 0xFFFF0000u); }

// ===========================================================================
// prep: blocks 0..39  -> cnt[i] = 1 (self-loops baked in)
//       blocks 40..47 -> pack W1 (f32 128x128) into MFMA B-fragment order:
//         slot s=(kk*8+ct)*64+l holds 8 bf16: B[k=kk*32+(l>>4)*8+j][ct*16+(l&15)]
// ===========================================================================
__global__ __launch_bounds__(256) void prep_kernel(
    const float* __restrict__ W1, int4* __restrict__ cnt4, ushort* __restrict__ Wf)
{
    if (blockIdx.x < 40) {
        const int i = blockIdx.x * 256 + threadIdx.x;
        if (i < 40064 / 4) cnt4[i] = make_int4(1, 1, 1, 1);
        return;
    }
    const int s = (blockIdx.x - 40) * 256 + threadIdx.x;   // 0..2047
    if (s >= 2048) return;
    const int kk = s >> 9;          // K-step (32 per step)
    const int rem = s & 511;
    const int ct = rem >> 6;        // column tile (16 cols)
    const int l = rem & 63;         // lane
    const int k0 = kk * 32 + (l >> 4) * 8;
    const int col = ct * 16 + (l & 15);
    uint4 o;
    o.x = pk_bf(W1[(k0 + 0) * 128 + col], W1[(k0 + 1) * 128 + col]);
    o.y = pk_bf(W1[(k0 + 2) * 128 + col], W1[(k0 + 3) * 128 + col]);
    o.z = pk_bf(W1[(k0 + 4) * 128 + col], W1[(k0 + 5) * 128 + col]);
    o.w = pk_bf(W1[(k0 + 6) * 128 + col], W1[(k0 + 7) * 128 + col]);
    ((uint4*)Wf)[s] = o;
}

// ===========================================================================
// GEMM1 (MFMA): h1 = x @ W1, 40000x128 @ 128x128, bf16 inputs, f32 accum.
// One wave = 16 rows x 128 cols (8 tiles of 16x16, K-loop 4 x 32).
// A-frag: lane l -> row l&15, k=(l>>4)*8+j (cvt from f32 x in-register).
// B-frag: coalesced 16B/lane from pre-packed Wf (L2-resident, no LDS).
// C/D: col=lane&15, row=(lane>>4)*4+reg  [m89-verified].
// Epilogue: h1b bf16 store + per-head attention dots via 16-lane shfl.
// Fused histogram tail (grid-stride over real edges; self-loops pre-baked).
// ===========================================================================
__global__ __launch_bounds__(256) void gemm1_kernel(
    const float* __restrict__ x, const ushort* __restrict__ Wf,
    const float* __restrict__ a_src, const float* __restrict__ a_dst,
    ushort* __restrict__ h1b, float* __restrict__ asrc, float* __restrict__ adst,
    const int* __restrict__ eidx, int* __restrict__ cnt)
{
    const int wv = threadIdx.x >> 6;
    const int lane = threadIdx.x & 63;
    const int rowbase = blockIdx.x * 64 + wv * 16;
    const int arow = rowbase + (lane & 15);
    const int kof = (lane >> 4) * 8;

    f32x4 acc0 = {0.f,0.f,0.f,0.f}, acc1 = {0.f,0.f,0.f,0.f};
    f32x4 acc2 = {0.f,0.f,0.f,0.f}, acc3 = {0.f,0.f,0.f,0.f};
    f32x4 acc4 = {0.f,0.f,0.f,0.f}, acc5 = {0.f,0.f,0.f,0.f};
    f32x4 acc6 = {0.f,0.f,0.f,0.f}, acc7 = {0.f,0.f,0.f,0.f};

    const short8v* WfV = (const short8v*)Wf;
#pragma unroll
    for (int kk = 0; kk < 4; ++kk) {
        const float* ap = &x[(size_t)arow * 128 + kk * 32 + kof];
        const float4 a0 = *(const float4*)ap;
        const float4 a1 = *(const float4*)(ap + 4);
        short8v af;
        af[0] = (short)f2bf(a0.x); af[1] = (short)f2bf(a0.y);
        af[2] = (short)f2bf(a0.z); af[3] = (short)f2bf(a0.w);
        af[4] = (short)f2bf(a1.x); af[5] = (short)f2bf(a1.y);
        af[6] = (short)f2bf(a1.z); af[7] = (short)f2bf(a1.w);
        const int base = kk * 8 * 64 + lane;
        acc0 = __builtin_amdgcn_mfma_f32_16x16x32_bf16(af, WfV[base + 0 * 64], acc0, 0, 0, 0);
        acc1 = __builtin_amdgcn_mfma_f32_16x16x32_bf16(af, WfV[base + 1 * 64], acc1, 0, 0, 0);
        acc2 = __builtin_amdgcn_mfma_f32_16x16x32_bf16(af, WfV[base + 2 * 64], acc2, 0, 0, 0);
        acc3 = __builtin_amdgcn_mfma_f32_16x16x32_bf16(af, WfV[base + 3 * 64], acc3, 0, 0, 0);
        acc4 = __builtin_amdgcn_mfma_f32_16x16x32_bf16(af, WfV[base + 4 * 64], acc4, 0, 0, 0);
        acc5 = __builtin_amdgcn_mfma_f32_16x16x32_bf16(af, WfV[base + 5 * 64], acc5, 0, 0, 0);
        acc6 = __builtin_amdgcn_mfma_f32_16x16x32_bf16(af, WfV[base + 6 * 64], acc6, 0, 0, 0);
        acc7 = __builtin_amdgcn_mfma_f32_16x16x32_bf16(af, WfV[base + 7 * 64], acc7, 0, 0, 0);
    }

    const int cl = lane & 15;   // col within tile
    const int rg = lane >> 4;   // row group
    float csA[8], cdA[8];
#pragma unroll
    for (int ct = 0; ct < 8; ++ct) {
        csA[ct] = a_src[(ct >> 1) * 32 + (ct & 1) * 16 + cl];
        cdA[ct] = a_dst[(ct >> 1) * 32 + (ct & 1) * 16 + cl];
    }
    const f32x4 accv[8] = { acc0, acc1, acc2, acc3, acc4, acc5, acc6, acc7 };
#pragma unroll
    for (int r = 0; r < 4; ++r) {
        const int n = rowbase + rg * 4 + r;
        ushort* hrow = &h1b[(size_t)n * 128 + cl];
#pragma unroll
        for (int ct = 0; ct < 8; ++ct) hrow[ct * 16] = f2bf(accv[ct][r]);
#pragma unroll
        for (int h = 0; h < 4; ++h) {
            float ps = accv[2 * h][r] * csA[2 * h] + accv[2 * h + 1][r] * csA[2 * h + 1];
            float pd = accv[2 * h][r] * cdA[2 * h] + accv[2 * h + 1][r] * cdA[2 * h + 1];
            ps += __shfl_xor(ps, 1); ps += __shfl_xor(ps, 2);
            ps += __shfl_xor(ps, 4); ps += __shfl_xor(ps, 8);
            pd += __shfl_xor(pd, 1); pd += __shfl_xor(pd, 2);
            pd += __shfl_xor(pd, 4); pd += __shfl_xor(pd, 8);
            if (cl == 0) { asrc[n * 4 + h] = ps; adst[n * 4 + h] = pd; }
        }
    }

    // ---- fused histogram tail (4 exact grid-stride steps) ----
    for (int e = blockIdx.x * 256 + threadIdx.x; e < E_EDGES; e += G1_BLOCKS * 256)
        atomicAdd(&cnt[eidx[E_EDGES + e]], 1);
}

// ===========================================================================
// scanA: block-local exclusive scan (incl. boundary slot); block total ->
// bsum; zeroes the fill cursor.
// ===========================================================================
__global__ __launch_bounds__(256) void scanA_kernel(
    const int* __restrict__ cnt, int* __restrict__ rowptr, int* __restrict__ bsum,
    int* __restrict__ cursor)
{
    const int i = blockIdx.x * 256 + threadIdx.x;
    const int lane = threadIdx.x & 63;
    const int wave = threadIdx.x >> 6;
    const int v = (i < N_NODES) ? cnt[i] : 0;
    int incl = v;
#pragma unroll
    for (int off = 1; off < 64; off <<= 1) {
        int u = __shfl_up(incl, off);
        if (lane >= off) incl += u;
    }
    __shared__ int ws[4];
    if (lane == 63) ws[wave] = incl;
    __syncthreads();
    int woff = 0;
    if (wave > 0) woff += ws[0];
    if (wave > 1) woff += ws[1];
    if (wave > 2) woff += ws[2];
    if (i <= N_NODES) rowptr[i] = woff + incl - v;   // block-local exclusive
    if (i < N_NODES) cursor[i] = 0;
    if (threadIdx.x == 255) bsum[blockIdx.x] = woff + incl;
}

// Single block: exclusive scan of the 157 block sums in place.
__global__ __launch_bounds__(256) void scanB_kernel(int* __restrict__ bsum)
{
    const int t = threadIdx.x;
    const int lane = t & 63;
    const int wave = t >> 6;
    const int v = (t < SCAN_BLOCKS) ? bsum[t] : 0;
    int incl = v;
#pragma unroll
    for (int off = 1; off < 64; off <<= 1) {
        int u = __shfl_up(incl, off);
        if (lane >= off) incl += u;
    }
    __shared__ int ws[4];
    if (lane == 63) ws[wave] = incl;
    __syncthreads();
    int woff = 0;
    if (wave > 0) woff += ws[0];
    if (wave > 1) woff += ws[1];
    if (wave > 2) woff += ws[2];
    if (t < SCAN_BLOCKS) bsum[t] = woff + incl - v;  // exclusive
}

// Bucket edges by dst (1 edge/thread, max TLP).
__global__ __launch_bounds__(256) void fill_kernel(
    const int* __restrict__ eidx, const int* __restrict__ rowptr,
    const int* __restrict__ bsum, int* __restrict__ cursor,
    int* __restrict__ esrc)
{
    const int e = blockIdx.x * 256 + threadIdx.x;
    if (e >= E_TOT) return;
    int s, d;
    if (e < E_EDGES) { s = eidx[e]; d = eidx[E_EDGES + e]; }
    else             { s = d = e - E_EDGES; }
    const int pos = atomicAdd(&cursor[d], 1);
    esrc[rowptr[d] + bsum[d >> 8] + pos] = s;
}

// ===========================================================================
// Gather pass 1: one wave per dst node; bf16 rows; 8-deep pipeline;
// fused normalize + bias + ELU.
// ===========================================================================
__global__ __launch_bounds__(256) void gather1_kernel(
    const int* __restrict__ rowptr, const int* __restrict__ bsum,
    const int* __restrict__ esrc, const float* __restrict__ asrc,
    const float* __restrict__ adst,
    const ushort* __restrict__ h1b, const float* __restrict__ b,
    float* __restrict__ agg)
{
    const int node = (blockIdx.x * 256 + threadIdx.x) >> 6;
    const int lane = threadIdx.x & 63;
    if (node >= N_NODES) return;
    const int head = lane >> 4;
    const float ad = adst[node * 4 + head];
    const int beg = rowptr[node] + bsum[node >> 8];
    const int end = rowptr[node + 1] + bsum[(node + 1) >> 8];
    float acc0 = 0.f, acc1 = 0.f, den = 0.f;

    int i = beg;
    for (; i + 8 <= end; i += 8) {
        int s[8];
        float a[8];
        uint w[8];
#pragma unroll
        for (int j = 0; j < 8; ++j) s[j] = esrc[i + j];
#pragma unroll
        for (int j = 0; j < 8; ++j) a[j] = asrc[s[j] * 4 + head];
#pragma unroll
        for (int j = 0; j < 8; ++j)
            w[j] = *(const uint*)&h1b[(size_t)s[j] * 128 + lane * 2];
#pragma unroll
        for (int j = 0; j < 8; ++j) {
            float v = a[j] + ad; v = v > 0.f ? v : 0.2f * v;
            const float e = __expf(v);
            den += e;
            acc0 = fmaf(e, bf_lo(w[j]), acc0);
            acc1 = fmaf(e, bf_hi(w[j]), acc1);
        }
    }
    for (; i < end; ++i) {
        const int s = esrc[i];
        float av = asrc[s * 4 + head] + ad;
        av = av > 0.f ? av : 0.2f * av;
        const float ex = __expf(av);
        const uint w = *(const uint*)&h1b[(size_t)s * 128 + lane * 2];
        den += ex;
        acc0 = fmaf(ex, bf_lo(w), acc0);
        acc1 = fmaf(ex, bf_hi(w), acc1);
    }

    const float inv = 1.f / (den + 1e-16f);
    const float2 bv = *(const float2*)&b[lane * 2];
    float o0 = acc0 * inv + bv.x;
    float o1 = acc1 * inv + bv.y;
    o0 = o0 > 0.f ? o0 : expm1f(o0);
    o1 = o1 > 0.f ? o1 : expm1f(o1);
    *(float2*)&agg[(size_t)node * 128 + lane * 2] = make_float2(o0, o1);
}

// ===========================================================================
// GEMM2: h2 = hin @ W2  [40000x128 @ 128x32], fused attention coeffs (1 head)
// ===========================================================================
__global__ __launch_bounds__(256) void gemm2_kernel(
    const float* __restrict__ hin, const float* __restrict__ W,
    const float* __restrict__ a_src, const float* __restrict__ a_dst,
    float* __restrict__ h2, float* __restrict__ asrc, float* __restrict__ adst)
{
    __shared__ float Ws[128 * 32];   // 16 KB
    {
        const float4* Wg = (const float4*)W;
        float4* Wl = (float4*)Ws;
        for (int i = threadIdx.x; i < 128 * 32 / 4; i += 256) Wl[i] = Wg[i];
    }
    __syncthreads();
    const int row0 = blockIdx.x * 64;
    const int tx = threadIdx.x & 7;
    const int ty = threadIdx.x >> 3;

    float acc[2][4];
#pragma unroll
    for (int r = 0; r < 2; ++r)
#pragma unroll
        for (int c = 0; c < 4; ++c) acc[r][c] = 0.f;

    for (int k0 = 0; k0 < 128; k0 += 4) {
        float xv[2][4];
#pragma unroll
        for (int r = 0; r < 2; ++r) {
            float4 t = *(const float4*)&hin[(size_t)(row0 + ty * 2 + r) * 128 + k0];
            xv[r][0] = t.x; xv[r][1] = t.y; xv[r][2] = t.z; xv[r][3] = t.w;
        }
#pragma unroll
        for (int kk = 0; kk < 4; ++kk) {
            float4 w = *(const float4*)&Ws[(k0 + kk) * 32 + tx * 4];
            float wreg[4] = { w.x, w.y, w.z, w.w };
#pragma unroll
            for (int r = 0; r < 2; ++r)
#pragma unroll
                for (int c = 0; c < 4; ++c)
                    acc[r][c] = fmaf(xv[r][kk], wreg[c], acc[r][c]);
        }
    }

    float as[4], ad[4];
#pragma unroll
    for (int c = 0; c < 4; ++c) {
        as[c] = a_src[tx * 4 + c];
        ad[c] = a_dst[tx * 4 + c];
    }
#pragma unroll
    for (int r = 0; r < 2; ++r) {
        const int n = row0 + ty * 2 + r;
        *(float4*)&h2[(size_t)n * 32 + tx * 4] =
            make_float4(acc[r][0], acc[r][1], acc[r][2], acc[r][3]);
        float ps = 0.f, pd = 0.f;
#pragma unroll
        for (int c = 0; c < 4; ++c) {
            ps = fmaf(acc[r][c], as[c], ps);
            pd = fmaf(acc[r][c], ad[c], pd);
        }
        ps += __shfl_xor(ps, 1); ps += __shfl_xor(ps, 2); ps += __shfl_xor(ps, 4);
        pd += __shfl_xor(pd, 1); pd += __shfl_xor(pd, 2); pd += __shfl_xor(pd, 4);
        if ((threadIdx.x & 7) == 0) { asrc[n] = ps; adst[n] = pd; }
    }
}

// ===========================================================================
// Gather pass 2: 32 lanes per dst node, 8-deep pipeline; fused norm+bias+ELU.
// ===========================================================================
__global__ __launch_bounds__(256) void gather2_kernel(
    const int* __restrict__ rowptr, const int* __restrict__ bsum,
    const int* __restrict__ esrc,
    const float* __restrict__ asrc, const float* __restrict__ adst,
    const float* __restrict__ h2, const float* __restrict__ b,
    float* __restrict__ agg)
{
    const int t = blockIdx.x * 256 + threadIdx.x;
    const int node = t >> 5;
    const int c = t & 31;
    if (node >= N_NODES) return;
    const float ad = adst[node];
    const int beg = rowptr[node] + bsum[node >> 8];
    const int end = rowptr[node + 1] + bsum[(node + 1) >> 8];
    float acc = 0.f, den = 0.f;

    int i = beg;
    for (; i + 8 <= end; i += 8) {
        int s[8];
        float a[8], h[8];
#pragma unroll
        for (int j = 0; j < 8; ++j) s[j] = esrc[i + j];
#pragma unroll
        for (int j = 0; j < 8; ++j) a[j] = asrc[s[j]];
#pragma unroll
        for (int j = 0; j < 8; ++j) h[j] = h2[(size_t)s[j] * 32 + c];
#pragma unroll
        for (int j = 0; j < 8; ++j) {
            float v = a[j] + ad; v = v > 0.f ? v : 0.2f * v;
            const float e = __expf(v);
            den += e;
            acc = fmaf(e, h[j], acc);
        }
    }
    for (; i < end; ++i) {
        const int s = esrc[i];
        float av = asrc[s] + ad;
        av = av > 0.f ? av : 0.2f * av;
        const float ex = __expf(av);
        den += ex;
        acc = fmaf(ex, h2[(size_t)s * 32 + c], acc);
    }

    const float inv = 1.f / (den + 1e-16f);
    float o = acc * inv + b[c];
    o = o > 0.f ? o : expm1f(o);
    agg[(size_t)node * 32 + c] = o;
}

// ===========================================================================
// Output GEMM: out = h3 @ W_out + b_out  [40000x32 @ 32x112]
// ===========================================================================
__global__ __launch_bounds__(256) void out_gemm_kernel(
    const float* __restrict__ h3, const float* __restrict__ W,
    const float* __restrict__ b, float* __restrict__ out)
{
    __shared__ float Ws[32 * 112];   // 14 KB
    {
        const float4* Wg = (const float4*)W;
        float4* Wl = (float4*)Ws;
        for (int i = threadIdx.x; i < 32 * 112 / 4; i += 256) Wl[i] = Wg[i];
    }
    __syncthreads();
    const int row0 = blockIdx.x * 32;
    const int tc = threadIdx.x & 15;
    const int tr = threadIdx.x >> 4;

    float acc[2][7];
#pragma unroll
    for (int r = 0; r < 2; ++r)
#pragma unroll
        for (int c = 0; c < 7; ++c) acc[r][c] = 0.f;

    for (int k0 = 0; k0 < 32; k0 += 4) {
        float xv[2][4];
#pragma unroll
        for (int r = 0; r < 2; ++r) {
            float4 t = *(const float4*)&h3[(size_t)(row0 + tr * 2 + r) * 32 + k0];
            xv[r][0] = t.x; xv[r][1] = t.y; xv[r][2] = t.z; xv[r][3] = t.w;
        }
#pragma unroll
        for (int kk = 0; kk < 4; ++kk) {
            float wv[7];
#pragma unroll
            for (int c = 0; c < 7; ++c) wv[c] = Ws[(k0 + kk) * 112 + tc * 7 + c];
#pragma unroll
            for (int r = 0; r < 2; ++r)
#pragma unroll
                for (int c = 0; c < 7; ++c)
                    acc[r][c] = fmaf(xv[r][kk], wv[c], acc[r][c]);
        }
    }
#pragma unroll
    for (int r = 0; r < 2; ++r) {
        const int n = row0 + tr * 2 + r;
#pragma unroll
        for (int c = 0; c < 7; ++c)
            out[(size_t)n * 112 + tc * 7 + c] = acc[r][c] + b[tc * 7 + c];
    }
}

// ===========================================================================
extern "C" void kernel_launch(void* const* d_in, const int* in_sizes, int n_in,
                              void* d_out, int out_size, void* d_ws, size_t ws_size,
                              hipStream_t stream) {
    const float* x      = (const float*)d_in[0];
    const int*   eidx   = (const int*)d_in[1];
    const float* W1     = (const float*)d_in[2];
    const float* a_src1 = (const float*)d_in[3];
    const float* a_dst1 = (const float*)d_in[4];
    const float* b1     = (const float*)d_in[5];
    const float* W2     = (const float*)d_in[6];
    const float* a_src2 = (const float*)d_in[7];
    const float* a_dst2 = (const float*)d_in[8];
    const float* b2     = (const float*)d_in[9];
    const float* W_out  = (const float*)d_in[10];
    const float* b_out  = (const float*)d_in[11];
    float* out = (float*)d_out;

    // ---- workspace layout (~35 MB) ----
    int* rowptr = (int*)d_ws;                 // 40064 (uses [0..40000])
    int* cnt    = rowptr + 40064;             // 40064 histogram
    int* cursor = cnt + 40064;                // 40064 fill cursor
    int* bsum   = cursor + 40064;             // 192 block sums (exclusive)
    ushort* Wf  = (ushort*)(bsum + 192);      // 16384 bf16 (32 KB, frag-ordered W1)
    int* esrc   = (int*)(Wf + 16384);         // 680000 CSR edge sources
    ushort* h1b  = (ushort*)(esrc + 680000);  // 40000*128 bf16
    float* asrc1 = (float*)(h1b + 5120000);   // 40000*4
    float* adst1 = asrc1 + 160000;            // 40000*4
    float* agg1  = adst1 + 160000;            // 40000*128
    // after gather1, h1b region is dead -> layer-2 buffers overlay it
    float* h2    = (float*)h1b;               // 40000*32
    float* asrc2 = h2 + 1280000;              // 40000
    float* adst2 = asrc2 + 40000;             // 40000
    float* agg2  = adst2 + 40000;             // 40000*32

    // cnt=1 init (self-loops baked) + W1 -> bf16 fragment pack
    prep_kernel<<<48, 256, 0, stream>>>(W1, (int4*)cnt, Wf);

    // Layer-1 GEMM (MFMA) + fused edge histogram
    gemm1_kernel<<<G1_BLOCKS, 256, 0, stream>>>(x, Wf, a_src1, a_dst1, h1b,
                                                asrc1, adst1, eidx, cnt);
    // CSR build (shared by both layers)
    scanA_kernel<<<SCAN_BLOCKS, 256, 0, stream>>>(cnt, rowptr, bsum, cursor);
    scanB_kernel<<<1, 256, 0, stream>>>(bsum);
    fill_kernel<<<(E_TOT + 255) / 256, 256, 0, stream>>>(
        eidx, rowptr, bsum, cursor, esrc);

    // Layer 1 aggregate
    gather1_kernel<<<10000, 256, 0, stream>>>(rowptr, bsum, esrc, asrc1, adst1,
                                              h1b, b1, agg1);

    // Layer 2
    gemm2_kernel<<<625, 256, 0, stream>>>(agg1, W2, a_src2, a_dst2, h2, asrc2, adst2);
    gather2_kernel<<<5000, 256, 0, stream>>>(rowptr, bsum, esrc, asrc2, adst2,
                                             h2, b2, agg2);

    // Output projection
    out_gemm_kernel<<<1250, 256, 0, stream>>>(agg2, W_out, b_out, out);
}

// Round 16
// 159.772 us; speedup vs baseline: 1.3931x; 1.0207x over previous
//
#include <hip/hip_runtime.h>

#define N_NODES 40000
#define E_EDGES 640000
#define E_TOT   (E_EDGES + N_NODES)
#define SCAN_BLOCKS ((N_NODES + 255) / 256)   // 157
#define G1_BLOCKS 625                         // 64 rows per block (4 waves x 16)
#define FILL_BLOCKS ((E_TOT + 255) / 256)     // 2657

typedef unsigned int uint;
typedef unsigned short ushort;
typedef __attribute__((ext_vector_type(8))) short short8v;   // 8 bf16 (4 VGPRs)
typedef __attribute__((ext_vector_type(4))) float f32x4;     // MFMA accumulator

// bf16 helpers (RNE pack, cheap unpack)
__device__ __forceinline__ ushort f2bf(float f) {
    uint u = __float_as_uint(f);
    u += 0x7FFFu + ((u >> 16) & 1u);
    return (ushort)(u >> 16);
}
__device__ __forceinline__ uint pk_bf(float lo, float hi) {
    return (uint)f2bf(lo) | ((uint)f2bf(hi) << 16);
}
__device__ __forceinline__ float bf_lo(uint w) { return __uint_as_float(w << 16); }
__device__ __forceinline__ float bf_hi(uint w) { return __uint_as_float(w & 0xFFFF0000u); }

// ===========================================================================
// prep: blocks 0..39  -> cnt[i] = 1 (self-loops baked in)
//       blocks 40..47 -> pack W1 (f32 128x128) into MFMA B-fragment order
// ===========================================================================
__global__ __launch_bounds__(256) void prep_kernel(
    const float* __restrict__ W1, int4* __restrict__ cnt4, ushort* __restrict__ Wf)
{
    if (blockIdx.x < 40) {
        const int i = blockIdx.x * 256 + threadIdx.x;
        if (i < 40064 / 4) cnt4[i] = make_int4(1, 1, 1, 1);
        return;
    }
    const int s = (blockIdx.x - 40) * 256 + threadIdx.x;   // 0..2047
    if (s >= 2048) return;
    const int kk = s >> 9;          // K-step (32 per step)
    const int rem = s & 511;
    const int ct = rem >> 6;        // column tile (16 cols)
    const int l = rem & 63;         // lane
    const int k0 = kk * 32 + (l >> 4) * 8;
    const int col = ct * 16 + (l & 15);
    uint4 o;
    o.x = pk_bf(W1[(k0 + 0) * 128 + col], W1[(k0 + 1) * 128 + col]);
    o.y = pk_bf(W1[(k0 + 2) * 128 + col], W1[(k0 + 3) * 128 + col]);
    o.z = pk_bf(W1[(k0 + 4) * 128 + col], W1[(k0 + 5) * 128 + col]);
    o.w = pk_bf(W1[(k0 + 6) * 128 + col], W1[(k0 + 7) * 128 + col]);
    ((uint4*)Wf)[s] = o;
}

// hist: 1 edge/thread (self-loops pre-baked in cnt init).
__global__ __launch_bounds__(256) void hist_kernel(
    const int* __restrict__ eidx, int* __restrict__ cnt)
{
    const int e = blockIdx.x * 256 + threadIdx.x;
    if (e < E_EDGES) atomicAdd(&cnt[eidx[E_EDGES + e]], 1);
}

// ===========================================================================
// scanA: block-local exclusive scan (incl. boundary slot); block total ->
// bsum; zeroes the fill cursor.
// ===========================================================================
__global__ __launch_bounds__(256) void scanA_kernel(
    const int* __restrict__ cnt, int* __restrict__ rowptr, int* __restrict__ bsum,
    int* __restrict__ cursor)
{
    const int i = blockIdx.x * 256 + threadIdx.x;
    const int lane = threadIdx.x & 63;
    const int wave = threadIdx.x >> 6;
    const int v = (i < N_NODES) ? cnt[i] : 0;
    int incl = v;
#pragma unroll
    for (int off = 1; off < 64; off <<= 1) {
        int u = __shfl_up(incl, off);
        if (lane >= off) incl += u;
    }
    __shared__ int ws[4];
    if (lane == 63) ws[wave] = incl;
    __syncthreads();
    int woff = 0;
    if (wave > 0) woff += ws[0];
    if (wave > 1) woff += ws[1];
    if (wave > 2) woff += ws[2];
    if (i <= N_NODES) rowptr[i] = woff + incl - v;   // block-local exclusive
    if (i < N_NODES) cursor[i] = 0;
    if (threadIdx.x == 255) bsum[blockIdx.x] = woff + incl;
}

// Single block: exclusive scan of the 157 block sums in place.
__global__ __launch_bounds__(256) void scanB_kernel(int* __restrict__ bsum)
{
    const int t = threadIdx.x;
    const int lane = t & 63;
    const int wave = t >> 6;
    const int v = (t < SCAN_BLOCKS) ? bsum[t] : 0;
    int incl = v;
#pragma unroll
    for (int off = 1; off < 64; off <<= 1) {
        int u = __shfl_up(incl, off);
        if (lane >= off) incl += u;
    }
    __shared__ int ws[4];
    if (lane == 63) ws[wave] = incl;
    __syncthreads();
    int woff = 0;
    if (wave > 0) woff += ws[0];
    if (wave > 1) woff += ws[1];
    if (wave > 2) woff += ws[2];
    if (t < SCAN_BLOCKS) bsum[t] = woff + incl - v;  // exclusive
}

// ===========================================================================
// FUSED gemm1 (MFMA) ∥ fill (block-range partition, independent work):
//   blocks [0, G1_BLOCKS)            -> MFMA GEMM tile (needs only x, Wf)
//   blocks [G1_BLOCKS, +FILL_BLOCKS) -> CSR bucket fill (needs scans, done)
// fill's atomic/scatter latency hides under gemm1's MFMA occupancy.
// ===========================================================================
__global__ __launch_bounds__(256) void gemm1_fill_kernel(
    const float* __restrict__ x, const ushort* __restrict__ Wf,
    const float* __restrict__ a_src, const float* __restrict__ a_dst,
    ushort* __restrict__ h1b, float* __restrict__ asrc, float* __restrict__ adst,
    const int* __restrict__ eidx, const int* __restrict__ rowptr,
    const int* __restrict__ bsum, int* __restrict__ cursor,
    int* __restrict__ esrc)
{
    if (blockIdx.x >= G1_BLOCKS) {
        // ---- fill partition: 1 edge/thread ----
        const int e = (blockIdx.x - G1_BLOCKS) * 256 + threadIdx.x;
        if (e >= E_TOT) return;
        int s, d;
        if (e < E_EDGES) { s = eidx[e]; d = eidx[E_EDGES + e]; }
        else             { s = d = e - E_EDGES; }
        const int pos = atomicAdd(&cursor[d], 1);
        esrc[rowptr[d] + bsum[d >> 8] + pos] = s;
        return;
    }

    // ---- gemm1 partition: one wave = 16 rows x 128 cols, K-loop 4 x 32 ----
    const int wv = threadIdx.x >> 6;
    const int lane = threadIdx.x & 63;
    const int rowbase = blockIdx.x * 64 + wv * 16;
    const int arow = rowbase + (lane & 15);
    const int kof = (lane >> 4) * 8;

    f32x4 acc0 = {0.f,0.f,0.f,0.f}, acc1 = {0.f,0.f,0.f,0.f};
    f32x4 acc2 = {0.f,0.f,0.f,0.f}, acc3 = {0.f,0.f,0.f,0.f};
    f32x4 acc4 = {0.f,0.f,0.f,0.f}, acc5 = {0.f,0.f,0.f,0.f};
    f32x4 acc6 = {0.f,0.f,0.f,0.f}, acc7 = {0.f,0.f,0.f,0.f};

    const short8v* WfV = (const short8v*)Wf;
#pragma unroll
    for (int kk = 0; kk < 4; ++kk) {
        const float* ap = &x[(size_t)arow * 128 + kk * 32 + kof];
        const float4 a0 = *(const float4*)ap;
        const float4 a1 = *(const float4*)(ap + 4);
        short8v af;
        af[0] = (short)f2bf(a0.x); af[1] = (short)f2bf(a0.y);
        af[2] = (short)f2bf(a0.z); af[3] = (short)f2bf(a0.w);
        af[4] = (short)f2bf(a1.x); af[5] = (short)f2bf(a1.y);
        af[6] = (short)f2bf(a1.z); af[7] = (short)f2bf(a1.w);
        const int base = kk * 8 * 64 + lane;
        acc0 = __builtin_amdgcn_mfma_f32_16x16x32_bf16(af, WfV[base + 0 * 64], acc0, 0, 0, 0);
        acc1 = __builtin_amdgcn_mfma_f32_16x16x32_bf16(af, WfV[base + 1 * 64], acc1, 0, 0, 0);
        acc2 = __builtin_amdgcn_mfma_f32_16x16x32_bf16(af, WfV[base + 2 * 64], acc2, 0, 0, 0);
        acc3 = __builtin_amdgcn_mfma_f32_16x16x32_bf16(af, WfV[base + 3 * 64], acc3, 0, 0, 0);
        acc4 = __builtin_amdgcn_mfma_f32_16x16x32_bf16(af, WfV[base + 4 * 64], acc4, 0, 0, 0);
        acc5 = __builtin_amdgcn_mfma_f32_16x16x32_bf16(af, WfV[base + 5 * 64], acc5, 0, 0, 0);
        acc6 = __builtin_amdgcn_mfma_f32_16x16x32_bf16(af, WfV[base + 6 * 64], acc6, 0, 0, 0);
        acc7 = __builtin_amdgcn_mfma_f32_16x16x32_bf16(af, WfV[base + 7 * 64], acc7, 0, 0, 0);
    }

    const int cl = lane & 15;   // col within tile
    const int rg = lane >> 4;   // row group
    float csA[8], cdA[8];
#pragma unroll
    for (int ct = 0; ct < 8; ++ct) {
        csA[ct] = a_src[(ct >> 1) * 32 + (ct & 1) * 16 + cl];
        cdA[ct] = a_dst[(ct >> 1) * 32 + (ct & 1) * 16 + cl];
    }
    const f32x4 accv[8] = { acc0, acc1, acc2, acc3, acc4, acc5, acc6, acc7 };
#pragma unroll
    for (int r = 0; r < 4; ++r) {
        const int n = rowbase + rg * 4 + r;
        ushort* hrow = &h1b[(size_t)n * 128 + cl];
#pragma unroll
        for (int ct = 0; ct < 8; ++ct) hrow[ct * 16] = f2bf(accv[ct][r]);
#pragma unroll
        for (int h = 0; h < 4; ++h) {
            float ps = accv[2 * h][r] * csA[2 * h] + accv[2 * h + 1][r] * csA[2 * h + 1];
            float pd = accv[2 * h][r] * cdA[2 * h] + accv[2 * h + 1][r] * cdA[2 * h + 1];
            ps += __shfl_xor(ps, 1); ps += __shfl_xor(ps, 2);
            ps += __shfl_xor(ps, 4); ps += __shfl_xor(ps, 8);
            pd += __shfl_xor(pd, 1); pd += __shfl_xor(pd, 2);
            pd += __shfl_xor(pd, 4); pd += __shfl_xor(pd, 8);
            if (cl == 0) { asrc[n * 4 + h] = ps; adst[n * 4 + h] = pd; }
        }
    }
}

// ===========================================================================
// Gather pass 1: one wave per dst node; bf16 rows; 8-deep pipeline;
// fused normalize + bias + ELU.
// ===========================================================================
__global__ __launch_bounds__(256) void gather1_kernel(
    const int* __restrict__ rowptr, const int* __restrict__ bsum,
    const int* __restrict__ esrc, const float* __restrict__ asrc,
    const float* __restrict__ adst,
    const ushort* __restrict__ h1b, const float* __restrict__ b,
    float* __restrict__ agg)
{
    const int node = (blockIdx.x * 256 + threadIdx.x) >> 6;
    const int lane = threadIdx.x & 63;
    if (node >= N_NODES) return;
    const int head = lane >> 4;
    const float ad = adst[node * 4 + head];
    const int beg = rowptr[node] + bsum[node >> 8];
    const int end = rowptr[node + 1] + bsum[(node + 1) >> 8];
    float acc0 = 0.f, acc1 = 0.f, den = 0.f;

    int i = beg;
    for (; i + 8 <= end; i += 8) {
        int s[8];
        float a[8];
        uint w[8];
#pragma unroll
        for (int j = 0; j < 8; ++j) s[j] = esrc[i + j];
#pragma unroll
        for (int j = 0; j < 8; ++j) a[j] = asrc[s[j] * 4 + head];
#pragma unroll
        for (int j = 0; j < 8; ++j)
            w[j] = *(const uint*)&h1b[(size_t)s[j] * 128 + lane * 2];
#pragma unroll
        for (int j = 0; j < 8; ++j) {
            float v = a[j] + ad; v = v > 0.f ? v : 0.2f * v;
            const float e = __expf(v);
            den += e;
            acc0 = fmaf(e, bf_lo(w[j]), acc0);
            acc1 = fmaf(e, bf_hi(w[j]), acc1);
        }
    }
    for (; i < end; ++i) {
        const int s = esrc[i];
        float av = asrc[s * 4 + head] + ad;
        av = av > 0.f ? av : 0.2f * av;
        const float ex = __expf(av);
        const uint w = *(const uint*)&h1b[(size_t)s * 128 + lane * 2];
        den += ex;
        acc0 = fmaf(ex, bf_lo(w), acc0);
        acc1 = fmaf(ex, bf_hi(w), acc1);
    }

    const float inv = 1.f / (den + 1e-16f);
    const float2 bv = *(const float2*)&b[lane * 2];
    float o0 = acc0 * inv + bv.x;
    float o1 = acc1 * inv + bv.y;
    o0 = o0 > 0.f ? o0 : expm1f(o0);
    o1 = o1 > 0.f ? o1 : expm1f(o1);
    *(float2*)&agg[(size_t)node * 128 + lane * 2] = make_float2(o0, o1);
}

// ===========================================================================
// GEMM2: h2 = hin @ W2  [40000x128 @ 128x32], fused attention coeffs (1 head)
// ===========================================================================
__global__ __launch_bounds__(256) void gemm2_kernel(
    const float* __restrict__ hin, const float* __restrict__ W,
    const float* __restrict__ a_src, const float* __restrict__ a_dst,
    float* __restrict__ h2, float* __restrict__ asrc, float* __restrict__ adst)
{
    __shared__ float Ws[128 * 32];   // 16 KB
    {
        const float4* Wg = (const float4*)W;
        float4* Wl = (float4*)Ws;
        for (int i = threadIdx.x; i < 128 * 32 / 4; i += 256) Wl[i] = Wg[i];
    }
    __syncthreads();
    const int row0 = blockIdx.x * 64;
    const int tx = threadIdx.x & 7;
    const int ty = threadIdx.x >> 3;

    float acc[2][4];
#pragma unroll
    for (int r = 0; r < 2; ++r)
#pragma unroll
        for (int c = 0; c < 4; ++c) acc[r][c] = 0.f;

    for (int k0 = 0; k0 < 128; k0 += 4) {
        float xv[2][4];
#pragma unroll
        for (int r = 0; r < 2; ++r) {
            float4 t = *(const float4*)&hin[(size_t)(row0 + ty * 2 + r) * 128 + k0];
            xv[r][0] = t.x; xv[r][1] = t.y; xv[r][2] = t.z; xv[r][3] = t.w;
        }
#pragma unroll
        for (int kk = 0; kk < 4; ++kk) {
            float4 w = *(const float4*)&Ws[(k0 + kk) * 32 + tx * 4];
            float wreg[4] = { w.x, w.y, w.z, w.w };
#pragma unroll
            for (int r = 0; r < 2; ++r)
#pragma unroll
                for (int c = 0; c < 4; ++c)
                    acc[r][c] = fmaf(xv[r][kk], wreg[c], acc[r][c]);
        }
    }

    float as[4], ad[4];
#pragma unroll
    for (int c = 0; c < 4; ++c) {
        as[c] = a_src[tx * 4 + c];
        ad[c] = a_dst[tx * 4 + c];
    }
#pragma unroll
    for (int r = 0; r < 2; ++r) {
        const int n = row0 + ty * 2 + r;
        *(float4*)&h2[(size_t)n * 32 + tx * 4] =
            make_float4(acc[r][0], acc[r][1], acc[r][2], acc[r][3]);
        float ps = 0.f, pd = 0.f;
#pragma unroll
        for (int c = 0; c < 4; ++c) {
            ps = fmaf(acc[r][c], as[c], ps);
            pd = fmaf(acc[r][c], ad[c], pd);
        }
        ps += __shfl_xor(ps, 1); ps += __shfl_xor(ps, 2); ps += __shfl_xor(ps, 4);
        pd += __shfl_xor(pd, 1); pd += __shfl_xor(pd, 2); pd += __shfl_xor(pd, 4);
        if ((threadIdx.x & 7) == 0) { asrc[n] = ps; adst[n] = pd; }
    }
}

// ===========================================================================
// Gather pass 2: 32 lanes per dst node, 8-deep pipeline; fused norm+bias+ELU.
// ===========================================================================
__global__ __launch_bounds__(256) void gather2_kernel(
    const int* __restrict__ rowptr, const int* __restrict__ bsum,
    const int* __restrict__ esrc,
    const float* __restrict__ asrc, const float* __restrict__ adst,
    const float* __restrict__ h2, const float* __restrict__ b,
    float* __restrict__ agg)
{
    const int t = blockIdx.x * 256 + threadIdx.x;
    const int node = t >> 5;
    const int c = t & 31;
    if (node >= N_NODES) return;
    const float ad = adst[node];
    const int beg = rowptr[node] + bsum[node >> 8];
    const int end = rowptr[node + 1] + bsum[(node + 1) >> 8];
    float acc = 0.f, den = 0.f;

    int i = beg;
    for (; i + 8 <= end; i += 8) {
        int s[8];
        float a[8], h[8];
#pragma unroll
        for (int j = 0; j < 8; ++j) s[j] = esrc[i + j];
#pragma unroll
        for (int j = 0; j < 8; ++j) a[j] = asrc[s[j]];
#pragma unroll
        for (int j = 0; j < 8; ++j) h[j] = h2[(size_t)s[j] * 32 + c];
#pragma unroll
        for (int j = 0; j < 8; ++j) {
            float v = a[j] + ad; v = v > 0.f ? v : 0.2f * v;
            const float e = __expf(v);
            den += e;
            acc = fmaf(e, h[j], acc);
        }
    }
    for (; i < end; ++i) {
        const int s = esrc[i];
        float av = asrc[s] + ad;
        av = av > 0.f ? av : 0.2f * av;
        const float ex = __expf(av);
        den += ex;
        acc = fmaf(ex, h2[(size_t)s * 32 + c], acc);
    }

    const float inv = 1.f / (den + 1e-16f);
    float o = acc * inv + b[c];
    o = o > 0.f ? o : expm1f(o);
    agg[(size_t)node * 32 + c] = o;
}

// ===========================================================================
// Output GEMM: out = h3 @ W_out + b_out  [40000x32 @ 32x112]
// ===========================================================================
__global__ __launch_bounds__(256) void out_gemm_kernel(
    const float* __restrict__ h3, const float* __restrict__ W,
    const float* __restrict__ b, float* __restrict__ out)
{
    __shared__ float Ws[32 * 112];   // 14 KB
    {
        const float4* Wg = (const float4*)W;
        float4* Wl = (float4*)Ws;
        for (int i = threadIdx.x; i < 32 * 112 / 4; i += 256) Wl[i] = Wg[i];
    }
    __syncthreads();
    const int row0 = blockIdx.x * 32;
    const int tc = threadIdx.x & 15;
    const int tr = threadIdx.x >> 4;

    float acc[2][7];
#pragma unroll
    for (int r = 0; r < 2; ++r)
#pragma unroll
        for (int c = 0; c < 7; ++c) acc[r][c] = 0.f;

    for (int k0 = 0; k0 < 32; k0 += 4) {
        float xv[2][4];
#pragma unroll
        for (int r = 0; r < 2; ++r) {
            float4 t = *(const float4*)&h3[(size_t)(row0 + tr * 2 + r) * 32 + k0];
            xv[r][0] = t.x; xv[r][1] = t.y; xv[r][2] = t.z; xv[r][3] = t.w;
        }
#pragma unroll
        for (int kk = 0; kk < 4; ++kk) {
            float wv[7];
#pragma unroll
            for (int c = 0; c < 7; ++c) wv[c] = Ws[(k0 + kk) * 112 + tc * 7 + c];
#pragma unroll
            for (int r = 0; r < 2; ++r)
#pragma unroll
                for (int c = 0; c < 7; ++c)
                    acc[r][c] = fmaf(xv[r][kk], wv[c], acc[r][c]);
        }
    }
#pragma unroll
    for (int r = 0; r < 2; ++r) {
        const int n = row0 + tr * 2 + r;
#pragma unroll
        for (int c = 0; c < 7; ++c)
            out[(size_t)n * 112 + tc * 7 + c] = acc[r][c] + b[tc * 7 + c];
    }
}

// ===========================================================================
extern "C" void kernel_launch(void* const* d_in, const int* in_sizes, int n_in,
                              void* d_out, int out_size, void* d_ws, size_t ws_size,
                              hipStream_t stream) {
    const float* x      = (const float*)d_in[0];
    const int*   eidx   = (const int*)d_in[1];
    const float* W1     = (const float*)d_in[2];
    const float* a_src1 = (const float*)d_in[3];
    const float* a_dst1 = (const float*)d_in[4];
    const float* b1     = (const float*)d_in[5];
    const float* W2     = (const float*)d_in[6];
    const float* a_src2 = (const float*)d_in[7];
    const float* a_dst2 = (const float*)d_in[8];
    const float* b2     = (const float*)d_in[9];
    const float* W_out  = (const float*)d_in[10];
    const float* b_out  = (const float*)d_in[11];
    float* out = (float*)d_out;

    // ---- workspace layout (~35 MB) ----
    int* rowptr = (int*)d_ws;                 // 40064 (uses [0..40000])
    int* cnt    = rowptr + 40064;             // 40064 histogram
    int* cursor = cnt + 40064;                // 40064 fill cursor
    int* bsum   = cursor + 40064;             // 192 block sums (exclusive)
    ushort* Wf  = (ushort*)(bsum + 192);      // 16384 bf16 (32 KB, frag-ordered W1)
    int* esrc   = (int*)(Wf + 16384);         // 680000 CSR edge sources
    ushort* h1b  = (ushort*)(esrc + 680000);  // 40000*128 bf16
    float* asrc1 = (float*)(h1b + 5120000);   // 40000*4
    float* adst1 = asrc1 + 160000;            // 40000*4
    float* agg1  = adst1 + 160000;            // 40000*128
    // after gather1, h1b region is dead -> layer-2 buffers overlay it
    float* h2    = (float*)h1b;               // 40000*32
    float* asrc2 = h2 + 1280000;              // 40000
    float* adst2 = asrc2 + 40000;             // 40000
    float* agg2  = adst2 + 40000;             // 40000*32

    // cnt=1 init (self-loops baked) + W1 -> bf16 fragment pack
    prep_kernel<<<48, 256, 0, stream>>>(W1, (int4*)cnt, Wf);

    // CSR histogram (critical path head; gemm1 overlaps later with fill)
    hist_kernel<<<(E_EDGES + 255) / 256, 256, 0, stream>>>(eidx, cnt);
    scanA_kernel<<<SCAN_BLOCKS, 256, 0, stream>>>(cnt, rowptr, bsum, cursor);
    scanB_kernel<<<1, 256, 0, stream>>>(bsum);

    // Layer-1 GEMM (MFMA) ∥ CSR bucket fill — independent block partitions
    gemm1_fill_kernel<<<G1_BLOCKS + FILL_BLOCKS, 256, 0, stream>>>(
        x, Wf, a_src1, a_dst1, h1b, asrc1, adst1,
        eidx, rowptr, bsum, cursor, esrc);

    // Layer 1 aggregate
    gather1_kernel<<<10000, 256, 0, stream>>>(rowptr, bsum, esrc, asrc1, adst1,
                                              h1b, b1, agg1);

    // Layer 2
    gemm2_kernel<<<625, 256, 0, stream>>>(agg1, W2, a_src2, a_dst2, h2, asrc2, adst2);
    gather2_kernel<<<5000, 256, 0, stream>>>(rowptr, bsum, esrc, asrc2, adst2,
                                             h2, b2, agg2);

    // Output projection
    out_gemm_kernel<<<1250, 256, 0, stream>>>(agg2, W_out, b_out, out);
}

// Round 17
// 136.123 us; speedup vs baseline: 1.6352x; 1.1737x over previous
//
#include <hip/hip_runtime.h>

#define N_NODES 40000
#define E_EDGES 640000
#define E_TOT   (E_EDGES + N_NODES)
#define SCAN_BLOCKS ((N_NODES + 255) / 256)   // 157
#define G1_BLOCKS 625                         // 64 rows per block (4 waves x 16)
#define HIST_BLOCKS ((E_EDGES + 255) / 256)   // 2500

typedef unsigned int uint;
typedef unsigned short ushort;
typedef __attribute__((ext_vector_type(8))) short short8v;   // 8 bf16 (4 VGPRs)
typedef __attribute__((ext_vector_type(4))) float f32x4;     // MFMA accumulator

// bf16 helpers (RNE pack, cheap unpack)
__device__ __forceinline__ ushort f2bf(float f) {
    uint u = __float_as_uint(f);
    u += 0x7FFFu + ((u >> 16) & 1u);
    return (ushort)(u >> 16);
}
__device__ __forceinline__ uint pk_bf(float lo, float hi) {
    return (uint)f2bf(lo) | ((uint)f2bf(hi) << 16);
}
__device__ __forceinline__ float bf_lo(uint w) { return __uint_as_float(w << 16); }
__device__ __forceinline__ float bf_hi(uint w) { return __uint_as_float(w & 0xFFFF0000u); }

// ===========================================================================
// prep: blocks 0..39  -> cnt[i] = 1 (self-loop baked in -> occupies rank 0)
//       blocks 40..47 -> pack W1 (f32 128x128) into MFMA B-fragment order
// ===========================================================================
__global__ __launch_bounds__(256) void prep_kernel(
    const float* __restrict__ W1, int4* __restrict__ cnt4, ushort* __restrict__ Wf)
{
    if (blockIdx.x < 40) {
        const int i = blockIdx.x * 256 + threadIdx.x;
        if (i < 40064 / 4) cnt4[i] = make_int4(1, 1, 1, 1);
        return;
    }
    const int s = (blockIdx.x - 40) * 256 + threadIdx.x;   // 0..2047
    if (s >= 2048) return;
    const int kk = s >> 9;          // K-step (32 per step)
    const int rem = s & 511;
    const int ct = rem >> 6;        // column tile (16 cols)
    const int l = rem & 63;         // lane
    const int k0 = kk * 32 + (l >> 4) * 8;
    const int col = ct * 16 + (l & 15);
    uint4 o;
    o.x = pk_bf(W1[(k0 + 0) * 128 + col], W1[(k0 + 1) * 128 + col]);
    o.y = pk_bf(W1[(k0 + 2) * 128 + col], W1[(k0 + 3) * 128 + col]);
    o.z = pk_bf(W1[(k0 + 4) * 128 + col], W1[(k0 + 5) * 128 + col]);
    o.w = pk_bf(W1[(k0 + 6) * 128 + col], W1[(k0 + 7) * 128 + col]);
    ((uint4*)Wf)[s] = o;
}

// ===========================================================================
// FUSED gemm1 (MFMA) ∥ hist+rank (block-range partition, independent):
//   blocks [0, G1_BLOCKS)            -> MFMA GEMM tile (needs only x, Wf)
//   blocks [G1_BLOCKS, +HIST_BLOCKS) -> histogram; rank[e] = old count
// The atomic's return value IS the edge's within-bucket rank -> fill needs
// no atomics at all.
// ===========================================================================
__global__ __launch_bounds__(256) void gemm1_hist_kernel(
    const float* __restrict__ x, const ushort* __restrict__ Wf,
    const float* __restrict__ a_src, const float* __restrict__ a_dst,
    ushort* __restrict__ h1b, float* __restrict__ asrc, float* __restrict__ adst,
    const int* __restrict__ eidx, int* __restrict__ cnt, int* __restrict__ rank)
{
    if (blockIdx.x >= G1_BLOCKS) {
        // ---- hist partition: 1 edge/thread; record rank ----
        const int e = (blockIdx.x - G1_BLOCKS) * 256 + threadIdx.x;
        if (e < E_EDGES)
            rank[e] = atomicAdd(&cnt[eidx[E_EDGES + e]], 1);
        return;
    }

    // ---- gemm1 partition: one wave = 16 rows x 128 cols, K-loop 4 x 32 ----
    const int wv = threadIdx.x >> 6;
    const int lane = threadIdx.x & 63;
    const int rowbase = blockIdx.x * 64 + wv * 16;
    const int arow = rowbase + (lane & 15);
    const int kof = (lane >> 4) * 8;

    f32x4 acc0 = {0.f,0.f,0.f,0.f}, acc1 = {0.f,0.f,0.f,0.f};
    f32x4 acc2 = {0.f,0.f,0.f,0.f}, acc3 = {0.f,0.f,0.f,0.f};
    f32x4 acc4 = {0.f,0.f,0.f,0.f}, acc5 = {0.f,0.f,0.f,0.f};
    f32x4 acc6 = {0.f,0.f,0.f,0.f}, acc7 = {0.f,0.f,0.f,0.f};

    const short8v* WfV = (const short8v*)Wf;
#pragma unroll
    for (int kk = 0; kk < 4; ++kk) {
        const float* ap = &x[(size_t)arow * 128 + kk * 32 + kof];
        const float4 a0 = *(const float4*)ap;
        const float4 a1 = *(const float4*)(ap + 4);
        short8v af;
        af[0] = (short)f2bf(a0.x); af[1] = (short)f2bf(a0.y);
        af[2] = (short)f2bf(a0.z); af[3] = (short)f2bf(a0.w);
        af[4] = (short)f2bf(a1.x); af[5] = (short)f2bf(a1.y);
        af[6] = (short)f2bf(a1.z); af[7] = (short)f2bf(a1.w);
        const int base = kk * 8 * 64 + lane;
        acc0 = __builtin_amdgcn_mfma_f32_16x16x32_bf16(af, WfV[base + 0 * 64], acc0, 0, 0, 0);
        acc1 = __builtin_amdgcn_mfma_f32_16x16x32_bf16(af, WfV[base + 1 * 64], acc1, 0, 0, 0);
        acc2 = __builtin_amdgcn_mfma_f32_16x16x32_bf16(af, WfV[base + 2 * 64], acc2, 0, 0, 0);
        acc3 = __builtin_amdgcn_mfma_f32_16x16x32_bf16(af, WfV[base + 3 * 64], acc3, 0, 0, 0);
        acc4 = __builtin_amdgcn_mfma_f32_16x16x32_bf16(af, WfV[base + 4 * 64], acc4, 0, 0, 0);
        acc5 = __builtin_amdgcn_mfma_f32_16x16x32_bf16(af, WfV[base + 5 * 64], acc5, 0, 0, 0);
        acc6 = __builtin_amdgcn_mfma_f32_16x16x32_bf16(af, WfV[base + 6 * 64], acc6, 0, 0, 0);
        acc7 = __builtin_amdgcn_mfma_f32_16x16x32_bf16(af, WfV[base + 7 * 64], acc7, 0, 0, 0);
    }

    const int cl = lane & 15;   // col within tile
    const int rg = lane >> 4;   // row group
    float csA[8], cdA[8];
#pragma unroll
    for (int ct = 0; ct < 8; ++ct) {
        csA[ct] = a_src[(ct >> 1) * 32 + (ct & 1) * 16 + cl];
        cdA[ct] = a_dst[(ct >> 1) * 32 + (ct & 1) * 16 + cl];
    }
    const f32x4 accv[8] = { acc0, acc1, acc2, acc3, acc4, acc5, acc6, acc7 };
#pragma unroll
    for (int r = 0; r < 4; ++r) {
        const int n = rowbase + rg * 4 + r;
        ushort* hrow = &h1b[(size_t)n * 128 + cl];
#pragma unroll
        for (int ct = 0; ct < 8; ++ct) hrow[ct * 16] = f2bf(accv[ct][r]);
#pragma unroll
        for (int h = 0; h < 4; ++h) {
            float ps = accv[2 * h][r] * csA[2 * h] + accv[2 * h + 1][r] * csA[2 * h + 1];
            float pd = accv[2 * h][r] * cdA[2 * h] + accv[2 * h + 1][r] * cdA[2 * h + 1];
            ps += __shfl_xor(ps, 1); ps += __shfl_xor(ps, 2);
            ps += __shfl_xor(ps, 4); ps += __shfl_xor(ps, 8);
            pd += __shfl_xor(pd, 1); pd += __shfl_xor(pd, 2);
            pd += __shfl_xor(pd, 4); pd += __shfl_xor(pd, 8);
            if (cl == 0) { asrc[n * 4 + h] = ps; adst[n * 4 + h] = pd; }
        }
    }
}

// ===========================================================================
// scanA: block-local exclusive scan (incl. boundary slot); block total -> bsum.
// ===========================================================================
__global__ __launch_bounds__(256) void scanA_kernel(
    const int* __restrict__ cnt, int* __restrict__ rowptr, int* __restrict__ bsum)
{
    const int i = blockIdx.x * 256 + threadIdx.x;
    const int lane = threadIdx.x & 63;
    const int wave = threadIdx.x >> 6;
    const int v = (i < N_NODES) ? cnt[i] : 0;
    int incl = v;
#pragma unroll
    for (int off = 1; off < 64; off <<= 1) {
        int u = __shfl_up(incl, off);
        if (lane >= off) incl += u;
    }
    __shared__ int ws[4];
    if (lane == 63) ws[wave] = incl;
    __syncthreads();
    int woff = 0;
    if (wave > 0) woff += ws[0];
    if (wave > 1) woff += ws[1];
    if (wave > 2) woff += ws[2];
    if (i <= N_NODES) rowptr[i] = woff + incl - v;   // block-local exclusive
    if (threadIdx.x == 255) bsum[blockIdx.x] = woff + incl;
}

// Single block: exclusive scan of the 157 block sums in place.
__global__ __launch_bounds__(256) void scanB_kernel(int* __restrict__ bsum)
{
    const int t = threadIdx.x;
    const int lane = t & 63;
    const int wave = t >> 6;
    const int v = (t < SCAN_BLOCKS) ? bsum[t] : 0;
    int incl = v;
#pragma unroll
    for (int off = 1; off < 64; off <<= 1) {
        int u = __shfl_up(incl, off);
        if (lane >= off) incl += u;
    }
    __shared__ int ws[4];
    if (lane == 63) ws[wave] = incl;
    __syncthreads();
    int woff = 0;
    if (wave > 0) woff += ws[0];
    if (wave > 1) woff += ws[1];
    if (wave > 2) woff += ws[2];
    if (t < SCAN_BLOCKS) bsum[t] = woff + incl - v;  // exclusive
}

// ===========================================================================
// fill (ATOMIC-FREE): esrc[rowptr[d] + bsum[d>>8] + rank[e]] = s.
// Self-loops (rank 0, baked into cnt init) handled by e >= E_EDGES lanes.
// ===========================================================================
__global__ __launch_bounds__(256) void fill_kernel(
    const int* __restrict__ eidx, const int* __restrict__ rowptr,
    const int* __restrict__ bsum, const int* __restrict__ rank,
    int* __restrict__ esrc)
{
    const int e = blockIdx.x * 256 + threadIdx.x;
    if (e >= E_TOT) return;
    int s, d, r;
    if (e < E_EDGES) { s = eidx[e]; d = eidx[E_EDGES + e]; r = rank[e]; }
    else             { s = d = e - E_EDGES; r = 0; }
    esrc[rowptr[d] + bsum[d >> 8] + r] = s;
}

// ===========================================================================
// Gather pass 1: one wave per dst node; bf16 rows; 8-deep pipeline;
// fused normalize + bias + ELU.
// ===========================================================================
__global__ __launch_bounds__(256) void gather1_kernel(
    const int* __restrict__ rowptr, const int* __restrict__ bsum,
    const int* __restrict__ esrc, const float* __restrict__ asrc,
    const float* __restrict__ adst,
    const ushort* __restrict__ h1b, const float* __restrict__ b,
    float* __restrict__ agg)
{
    const int node = (blockIdx.x * 256 + threadIdx.x) >> 6;
    const int lane = threadIdx.x & 63;
    if (node >= N_NODES) return;
    const int head = lane >> 4;
    const float ad = adst[node * 4 + head];
    const int beg = rowptr[node] + bsum[node >> 8];
    const int end = rowptr[node + 1] + bsum[(node + 1) >> 8];
    float acc0 = 0.f, acc1 = 0.f, den = 0.f;

    int i = beg;
    for (; i + 8 <= end; i += 8) {
        int s[8];
        float a[8];
        uint w[8];
#pragma unroll
        for (int j = 0; j < 8; ++j) s[j] = esrc[i + j];
#pragma unroll
        for (int j = 0; j < 8; ++j) a[j] = asrc[s[j] * 4 + head];
#pragma unroll
        for (int j = 0; j < 8; ++j)
            w[j] = *(const uint*)&h1b[(size_t)s[j] * 128 + lane * 2];
#pragma unroll
        for (int j = 0; j < 8; ++j) {
            float v = a[j] + ad; v = v > 0.f ? v : 0.2f * v;
            const float e = __expf(v);
            den += e;
            acc0 = fmaf(e, bf_lo(w[j]), acc0);
            acc1 = fmaf(e, bf_hi(w[j]), acc1);
        }
    }
    for (; i < end; ++i) {
        const int s = esrc[i];
        float av = asrc[s * 4 + head] + ad;
        av = av > 0.f ? av : 0.2f * av;
        const float ex = __expf(av);
        const uint w = *(const uint*)&h1b[(size_t)s * 128 + lane * 2];
        den += ex;
        acc0 = fmaf(ex, bf_lo(w), acc0);
        acc1 = fmaf(ex, bf_hi(w), acc1);
    }

    const float inv = 1.f / (den + 1e-16f);
    const float2 bv = *(const float2*)&b[lane * 2];
    float o0 = acc0 * inv + bv.x;
    float o1 = acc1 * inv + bv.y;
    o0 = o0 > 0.f ? o0 : expm1f(o0);
    o1 = o1 > 0.f ? o1 : expm1f(o1);
    *(float2*)&agg[(size_t)node * 128 + lane * 2] = make_float2(o0, o1);
}

// ===========================================================================
// GEMM2: h2 = hin @ W2  [40000x128 @ 128x32], fused attention coeffs (1 head)
// ===========================================================================
__global__ __launch_bounds__(256) void gemm2_kernel(
    const float* __restrict__ hin, const float* __restrict__ W,
    const float* __restrict__ a_src, const float* __restrict__ a_dst,
    float* __restrict__ h2, float* __restrict__ asrc, float* __restrict__ adst)
{
    __shared__ float Ws[128 * 32];   // 16 KB
    {
        const float4* Wg = (const float4*)W;
        float4* Wl = (float4*)Ws;
        for (int i = threadIdx.x; i < 128 * 32 / 4; i += 256) Wl[i] = Wg[i];
    }
    __syncthreads();
    const int row0 = blockIdx.x * 64;
    const int tx = threadIdx.x & 7;
    const int ty = threadIdx.x >> 3;

    float acc[2][4];
#pragma unroll
    for (int r = 0; r < 2; ++r)
#pragma unroll
        for (int c = 0; c < 4; ++c) acc[r][c] = 0.f;

    for (int k0 = 0; k0 < 128; k0 += 4) {
        float xv[2][4];
#pragma unroll
        for (int r = 0; r < 2; ++r) {
            float4 t = *(const float4*)&hin[(size_t)(row0 + ty * 2 + r) * 128 + k0];
            xv[r][0] = t.x; xv[r][1] = t.y; xv[r][2] = t.z; xv[r][3] = t.w;
        }
#pragma unroll
        for (int kk = 0; kk < 4; ++kk) {
            float4 w = *(const float4*)&Ws[(k0 + kk) * 32 + tx * 4];
            float wreg[4] = { w.x, w.y, w.z, w.w };
#pragma unroll
            for (int r = 0; r < 2; ++r)
#pragma unroll
                for (int c = 0; c < 4; ++c)
                    acc[r][c] = fmaf(xv[r][kk], wreg[c], acc[r][c]);
        }
    }

    float as[4], ad[4];
#pragma unroll
    for (int c = 0; c < 4; ++c) {
        as[c] = a_src[tx * 4 + c];
        ad[c] = a_dst[tx * 4 + c];
    }
#pragma unroll
    for (int r = 0; r < 2; ++r) {
        const int n = row0 + ty * 2 + r;
        *(float4*)&h2[(size_t)n * 32 + tx * 4] =
            make_float4(acc[r][0], acc[r][1], acc[r][2], acc[r][3]);
        float ps = 0.f, pd = 0.f;
#pragma unroll
        for (int c = 0; c < 4; ++c) {
            ps = fmaf(acc[r][c], as[c], ps);
            pd = fmaf(acc[r][c], ad[c], pd);
        }
        ps += __shfl_xor(ps, 1); ps += __shfl_xor(ps, 2); ps += __shfl_xor(ps, 4);
        pd += __shfl_xor(pd, 1); pd += __shfl_xor(pd, 2); pd += __shfl_xor(pd, 4);
        if ((threadIdx.x & 7) == 0) { asrc[n] = ps; adst[n] = pd; }
    }
}

// ===========================================================================
// Gather pass 2: 32 lanes per dst node, 8-deep pipeline; fused norm+bias+ELU.
// ===========================================================================
__global__ __launch_bounds__(256) void gather2_kernel(
    const int* __restrict__ rowptr, const int* __restrict__ bsum,
    const int* __restrict__ esrc,
    const float* __restrict__ asrc, const float* __restrict__ adst,
    const float* __restrict__ h2, const float* __restrict__ b,
    float* __restrict__ agg)
{
    const int t = blockIdx.x * 256 + threadIdx.x;
    const int node = t >> 5;
    const int c = t & 31;
    if (node >= N_NODES) return;
    const float ad = adst[node];
    const int beg = rowptr[node] + bsum[node >> 8];
    const int end = rowptr[node + 1] + bsum[(node + 1) >> 8];
    float acc = 0.f, den = 0.f;

    int i = beg;
    for (; i + 8 <= end; i += 8) {
        int s[8];
        float a[8], h[8];
#pragma unroll
        for (int j = 0; j < 8; ++j) s[j] = esrc[i + j];
#pragma unroll
        for (int j = 0; j < 8; ++j) a[j] = asrc[s[j]];
#pragma unroll
        for (int j = 0; j < 8; ++j) h[j] = h2[(size_t)s[j] * 32 + c];
#pragma unroll
        for (int j = 0; j < 8; ++j) {
            float v = a[j] + ad; v = v > 0.f ? v : 0.2f * v;
            const float e = __expf(v);
            den += e;
            acc = fmaf(e, h[j], acc);
        }
    }
    for (; i < end; ++i) {
        const int s = esrc[i];
        float av = asrc[s] + ad;
        av = av > 0.f ? av : 0.2f * av;
        const float ex = __expf(av);
        den += ex;
        acc = fmaf(ex, h2[(size_t)s * 32 + c], acc);
    }

    const float inv = 1.f / (den + 1e-16f);
    float o = acc * inv + b[c];
    o = o > 0.f ? o : expm1f(o);
    agg[(size_t)node * 32 + c] = o;
}

// ===========================================================================
// Output GEMM: out = h3 @ W_out + b_out  [40000x32 @ 32x112]
// ===========================================================================
__global__ __launch_bounds__(256) void out_gemm_kernel(
    const float* __restrict__ h3, const float* __restrict__ W,
    const float* __restrict__ b, float* __restrict__ out)
{
    __shared__ float Ws[32 * 112];   // 14 KB
    {
        const float4* Wg = (const float4*)W;
        float4* Wl = (float4*)Ws;
        for (int i = threadIdx.x; i < 32 * 112 / 4; i += 256) Wl[i] = Wg[i];
    }
    __syncthreads();
    const int row0 = blockIdx.x * 32;
    const int tc = threadIdx.x & 15;
    const int tr = threadIdx.x >> 4;

    float acc[2][7];
#pragma unroll
    for (int r = 0; r < 2; ++r)
#pragma unroll
        for (int c = 0; c < 7; ++c) acc[r][c] = 0.f;

    for (int k0 = 0; k0 < 32; k0 += 4) {
        float xv[2][4];
#pragma unroll
        for (int r = 0; r < 2; ++r) {
            float4 t = *(const float4*)&h3[(size_t)(row0 + tr * 2 + r) * 32 + k0];
            xv[r][0] = t.x; xv[r][1] = t.y; xv[r][2] = t.z; xv[r][3] = t.w;
        }
#pragma unroll
        for (int kk = 0; kk < 4; ++kk) {
            float wv[7];
#pragma unroll
            for (int c = 0; c < 7; ++c) wv[c] = Ws[(k0 + kk) * 112 + tc * 7 + c];
#pragma unroll
            for (int r = 0; r < 2; ++r)
#pragma unroll
                for (int c = 0; c < 7; ++c)
                    acc[r][c] = fmaf(xv[r][kk], wv[c], acc[r][c]);
        }
    }
#pragma unroll
    for (int r = 0; r < 2; ++r) {
        const int n = row0 + tr * 2 + r;
#pragma unroll
        for (int c = 0; c < 7; ++c)
            out[(size_t)n * 112 + tc * 7 + c] = acc[r][c] + b[tc * 7 + c];
    }
}

// ===========================================================================
extern "C" void kernel_launch(void* const* d_in, const int* in_sizes, int n_in,
                              void* d_out, int out_size, void* d_ws, size_t ws_size,
                              hipStream_t stream) {
    const float* x      = (const float*)d_in[0];
    const int*   eidx   = (const int*)d_in[1];
    const float* W1     = (const float*)d_in[2];
    const float* a_src1 = (const float*)d_in[3];
    const float* a_dst1 = (const float*)d_in[4];
    const float* b1     = (const float*)d_in[5];
    const float* W2     = (const float*)d_in[6];
    const float* a_src2 = (const float*)d_in[7];
    const float* a_dst2 = (const float*)d_in[8];
    const float* b2     = (const float*)d_in[9];
    const float* W_out  = (const float*)d_in[10];
    const float* b_out  = (const float*)d_in[11];
    float* out = (float*)d_out;

    // ---- workspace layout (~38 MB) ----
    int* rowptr = (int*)d_ws;                 // 40064 (uses [0..40000])
    int* cnt    = rowptr + 40064;             // 40064 histogram (init = 1)
    int* bsum   = cnt + 40064;                // 192 block sums (exclusive)
    int* rank   = bsum + 192;                 // 680000 per-edge bucket rank
    ushort* Wf  = (ushort*)(rank + 680000);   // 16384 bf16 (32 KB, frag-ordered W1)
    int* esrc   = (int*)(Wf + 16384);         // 680000 CSR edge sources
    ushort* h1b  = (ushort*)(esrc + 680000);  // 40000*128 bf16
    float* asrc1 = (float*)(h1b + 5120000);   // 40000*4
    float* adst1 = asrc1 + 160000;            // 40000*4
    float* agg1  = adst1 + 160000;            // 40000*128
    // after gather1, h1b region is dead -> layer-2 buffers overlay it
    float* h2    = (float*)h1b;               // 40000*32
    float* asrc2 = h2 + 1280000;              // 40000
    float* adst2 = asrc2 + 40000;             // 40000
    float* agg2  = adst2 + 40000;             // 40000*32

    // cnt=1 init (self-loops -> rank 0) + W1 -> bf16 fragment pack
    prep_kernel<<<48, 256, 0, stream>>>(W1, (int4*)cnt, Wf);

    // Layer-1 GEMM (MFMA) ∥ histogram-with-rank — independent block partitions
    gemm1_hist_kernel<<<G1_BLOCKS + HIST_BLOCKS, 256, 0, stream>>>(
        x, Wf, a_src1, a_dst1, h1b, asrc1, adst1, eidx, cnt, rank);

    // CSR scan
    scanA_kernel<<<SCAN_BLOCKS, 256, 0, stream>>>(cnt, rowptr, bsum);
    scanB_kernel<<<1, 256, 0, stream>>>(bsum);

    // Atomic-free bucket fill
    fill_kernel<<<(E_TOT + 255) / 256, 256, 0, stream>>>(
        eidx, rowptr, bsum, rank, esrc);

    // Layer 1 aggregate
    gather1_kernel<<<10000, 256, 0, stream>>>(rowptr, bsum, esrc, asrc1, adst1,
                                              h1b, b1, agg1);

    // Layer 2
    gemm2_kernel<<<625, 256, 0, stream>>>(agg1, W2, a_src2, a_dst2, h2, asrc2, adst2);
    gather2_kernel<<<5000, 256, 0, stream>>>(rowptr, bsum, esrc, asrc2, adst2,
                                             h2, b2, agg2);

    // Output projection
    out_gemm_kernel<<<1250, 256, 0, stream>>>(agg2, W_out, b_out, out);
}

// Round 18
// 133.027 us; speedup vs baseline: 1.6732x; 1.0233x over previous
//
#include <hip/hip_runtime.h>

#define N_NODES 40000
#define E_EDGES 640000
#define E_TOT   (E_EDGES + N_NODES)
#define SCAN_BLOCKS ((N_NODES + 255) / 256)   // 157
#define G1_BLOCKS 625                         // 64 rows per block (4 waves x 16)
#define HIST_BLOCKS ((E_EDGES + 255) / 256)   // 2500

typedef unsigned int uint;
typedef unsigned short ushort;
typedef __attribute__((ext_vector_type(8))) short short8v;   // 8 bf16 (4 VGPRs)
typedef __attribute__((ext_vector_type(4))) float f32x4;     // MFMA accumulator

// bf16 helpers (RNE pack, cheap unpack)
__device__ __forceinline__ ushort f2bf(float f) {
    uint u = __float_as_uint(f);
    u += 0x7FFFu + ((u >> 16) & 1u);
    return (ushort)(u >> 16);
}
__device__ __forceinline__ uint pk_bf(float lo, float hi) {
    return (uint)f2bf(lo) | ((uint)f2bf(hi) << 16);
}
__device__ __forceinline__ float bf_lo(uint w) { return __uint_as_float(w << 16); }
__device__ __forceinline__ float bf_hi(uint w) { return __uint_as_float(w & 0xFFFF0000u); }

// ===========================================================================
// prep: blocks 0..39  -> cnt[i] = 1 (self-loop baked in -> occupies rank 0)
//       blocks 40..47 -> pack W1 (f32 128x128) into MFMA B-fragment order
// ===========================================================================
__global__ __launch_bounds__(256) void prep_kernel(
    const float* __restrict__ W1, int4* __restrict__ cnt4, ushort* __restrict__ Wf)
{
    if (blockIdx.x < 40) {
        const int i = blockIdx.x * 256 + threadIdx.x;
        if (i < 40064 / 4) cnt4[i] = make_int4(1, 1, 1, 1);
        return;
    }
    const int s = (blockIdx.x - 40) * 256 + threadIdx.x;   // 0..2047
    if (s >= 2048) return;
    const int kk = s >> 9;          // K-step (32 per step)
    const int rem = s & 511;
    const int ct = rem >> 6;        // column tile (16 cols)
    const int l = rem & 63;         // lane
    const int k0 = kk * 32 + (l >> 4) * 8;
    const int col = ct * 16 + (l & 15);
    uint4 o;
    o.x = pk_bf(W1[(k0 + 0) * 128 + col], W1[(k0 + 1) * 128 + col]);
    o.y = pk_bf(W1[(k0 + 2) * 128 + col], W1[(k0 + 3) * 128 + col]);
    o.z = pk_bf(W1[(k0 + 4) * 128 + col], W1[(k0 + 5) * 128 + col]);
    o.w = pk_bf(W1[(k0 + 6) * 128 + col], W1[(k0 + 7) * 128 + col]);
    ((uint4*)Wf)[s] = o;
}

// ===========================================================================
// FUSED gemm1 (MFMA) ∥ hist+rank (block-range partition, independent):
//   blocks [0, G1_BLOCKS)            -> MFMA GEMM tile (needs only x, Wf)
//   blocks [G1_BLOCKS, +HIST_BLOCKS) -> histogram; rank[e] = old count
// ===========================================================================
__global__ __launch_bounds__(256) void gemm1_hist_kernel(
    const float* __restrict__ x, const ushort* __restrict__ Wf,
    const float* __restrict__ a_src, const float* __restrict__ a_dst,
    ushort* __restrict__ h1b, float* __restrict__ asrc, float* __restrict__ adst,
    const int* __restrict__ eidx, int* __restrict__ cnt, int* __restrict__ rank)
{
    if (blockIdx.x >= G1_BLOCKS) {
        // ---- hist partition: 1 edge/thread; record rank ----
        const int e = (blockIdx.x - G1_BLOCKS) * 256 + threadIdx.x;
        if (e < E_EDGES)
            rank[e] = atomicAdd(&cnt[eidx[E_EDGES + e]], 1);
        return;
    }

    // ---- gemm1 partition: one wave = 16 rows x 128 cols, K-loop 4 x 32 ----
    const int wv = threadIdx.x >> 6;
    const int lane = threadIdx.x & 63;
    const int rowbase = blockIdx.x * 64 + wv * 16;
    const int arow = rowbase + (lane & 15);
    const int kof = (lane >> 4) * 8;

    f32x4 acc0 = {0.f,0.f,0.f,0.f}, acc1 = {0.f,0.f,0.f,0.f};
    f32x4 acc2 = {0.f,0.f,0.f,0.f}, acc3 = {0.f,0.f,0.f,0.f};
    f32x4 acc4 = {0.f,0.f,0.f,0.f}, acc5 = {0.f,0.f,0.f,0.f};
    f32x4 acc6 = {0.f,0.f,0.f,0.f}, acc7 = {0.f,0.f,0.f,0.f};

    const short8v* WfV = (const short8v*)Wf;
#pragma unroll
    for (int kk = 0; kk < 4; ++kk) {
        const float* ap = &x[(size_t)arow * 128 + kk * 32 + kof];
        const float4 a0 = *(const float4*)ap;
        const float4 a1 = *(const float4*)(ap + 4);
        short8v af;
        af[0] = (short)f2bf(a0.x); af[1] = (short)f2bf(a0.y);
        af[2] = (short)f2bf(a0.z); af[3] = (short)f2bf(a0.w);
        af[4] = (short)f2bf(a1.x); af[5] = (short)f2bf(a1.y);
        af[6] = (short)f2bf(a1.z); af[7] = (short)f2bf(a1.w);
        const int base = kk * 8 * 64 + lane;
        acc0 = __builtin_amdgcn_mfma_f32_16x16x32_bf16(af, WfV[base + 0 * 64], acc0, 0, 0, 0);
        acc1 = __builtin_amdgcn_mfma_f32_16x16x32_bf16(af, WfV[base + 1 * 64], acc1, 0, 0, 0);
        acc2 = __builtin_amdgcn_mfma_f32_16x16x32_bf16(af, WfV[base + 2 * 64], acc2, 0, 0, 0);
        acc3 = __builtin_amdgcn_mfma_f32_16x16x32_bf16(af, WfV[base + 3 * 64], acc3, 0, 0, 0);
        acc4 = __builtin_amdgcn_mfma_f32_16x16x32_bf16(af, WfV[base + 4 * 64], acc4, 0, 0, 0);
        acc5 = __builtin_amdgcn_mfma_f32_16x16x32_bf16(af, WfV[base + 5 * 64], acc5, 0, 0, 0);
        acc6 = __builtin_amdgcn_mfma_f32_16x16x32_bf16(af, WfV[base + 6 * 64], acc6, 0, 0, 0);
        acc7 = __builtin_amdgcn_mfma_f32_16x16x32_bf16(af, WfV[base + 7 * 64], acc7, 0, 0, 0);
    }

    const int cl = lane & 15;   // col within tile
    const int rg = lane >> 4;   // row group
    float csA[8], cdA[8];
#pragma unroll
    for (int ct = 0; ct < 8; ++ct) {
        csA[ct] = a_src[(ct >> 1) * 32 + (ct & 1) * 16 + cl];
        cdA[ct] = a_dst[(ct >> 1) * 32 + (ct & 1) * 16 + cl];
    }
    const f32x4 accv[8] = { acc0, acc1, acc2, acc3, acc4, acc5, acc6, acc7 };
#pragma unroll
    for (int r = 0; r < 4; ++r) {
        const int n = rowbase + rg * 4 + r;
        ushort* hrow = &h1b[(size_t)n * 128 + cl];
#pragma unroll
        for (int ct = 0; ct < 8; ++ct) hrow[ct * 16] = f2bf(accv[ct][r]);
#pragma unroll
        for (int h = 0; h < 4; ++h) {
            float ps = accv[2 * h][r] * csA[2 * h] + accv[2 * h + 1][r] * csA[2 * h + 1];
            float pd = accv[2 * h][r] * cdA[2 * h] + accv[2 * h + 1][r] * cdA[2 * h + 1];
            ps += __shfl_xor(ps, 1); ps += __shfl_xor(ps, 2);
            ps += __shfl_xor(ps, 4); ps += __shfl_xor(ps, 8);
            pd += __shfl_xor(pd, 1); pd += __shfl_xor(pd, 2);
            pd += __shfl_xor(pd, 4); pd += __shfl_xor(pd, 8);
            if (cl == 0) { asrc[n * 4 + h] = ps; adst[n * 4 + h] = pd; }
        }
    }
}

// ===========================================================================
// scanA: block-local exclusive scan (incl. boundary slot); block total -> bsum.
// ===========================================================================
__global__ __launch_bounds__(256) void scanA_kernel(
    const int* __restrict__ cnt, int* __restrict__ rowptr, int* __restrict__ bsum)
{
    const int i = blockIdx.x * 256 + threadIdx.x;
    const int lane = threadIdx.x & 63;
    const int wave = threadIdx.x >> 6;
    const int v = (i < N_NODES) ? cnt[i] : 0;
    int incl = v;
#pragma unroll
    for (int off = 1; off < 64; off <<= 1) {
        int u = __shfl_up(incl, off);
        if (lane >= off) incl += u;
    }
    __shared__ int ws[4];
    if (lane == 63) ws[wave] = incl;
    __syncthreads();
    int woff = 0;
    if (wave > 0) woff += ws[0];
    if (wave > 1) woff += ws[1];
    if (wave > 2) woff += ws[2];
    if (i <= N_NODES) rowptr[i] = woff + incl - v;   // block-local exclusive
    if (threadIdx.x == 255) bsum[blockIdx.x] = woff + incl;
}

// Single block: exclusive scan of the 157 block sums in place.
__global__ __launch_bounds__(256) void scanB_kernel(int* __restrict__ bsum)
{
    const int t = threadIdx.x;
    const int lane = t & 63;
    const int wave = t >> 6;
    const int v = (t < SCAN_BLOCKS) ? bsum[t] : 0;
    int incl = v;
#pragma unroll
    for (int off = 1; off < 64; off <<= 1) {
        int u = __shfl_up(incl, off);
        if (lane >= off) incl += u;
    }
    __shared__ int ws[4];
    if (lane == 63) ws[wave] = incl;
    __syncthreads();
    int woff = 0;
    if (wave > 0) woff += ws[0];
    if (wave > 1) woff += ws[1];
    if (wave > 2) woff += ws[2];
    if (t < SCAN_BLOCKS) bsum[t] = woff + incl - v;  // exclusive
}

// ===========================================================================
// fill (ATOMIC-FREE): esrc[rowptr[d] + bsum[d>>8] + rank[e]] = s.
// ===========================================================================
__global__ __launch_bounds__(256) void fill_kernel(
    const int* __restrict__ eidx, const int* __restrict__ rowptr,
    const int* __restrict__ bsum, const int* __restrict__ rank,
    int* __restrict__ esrc)
{
    const int e = blockIdx.x * 256 + threadIdx.x;
    if (e >= E_TOT) return;
    int s, d, r;
    if (e < E_EDGES) { s = eidx[e]; d = eidx[E_EDGES + e]; r = rank[e]; }
    else             { s = d = e - E_EDGES; r = 0; }
    esrc[rowptr[d] + bsum[d >> 8] + r] = s;
}

// ===========================================================================
// Gather pass 1: 32 lanes per dst node (2 nodes/wave) — doubles the per-wave
// memory-level parallelism (16 independent row loads in flight). Each lane
// covers 4 bf16 channels (uint2 8B load); 8-deep pipeline per node;
// fused normalize + bias + ELU (float4 store).
// ===========================================================================
__global__ __launch_bounds__(256) void gather1_kernel(
    const int* __restrict__ rowptr, const int* __restrict__ bsum,
    const int* __restrict__ esrc, const float* __restrict__ asrc,
    const float* __restrict__ adst,
    const ushort* __restrict__ h1b, const float* __restrict__ b,
    float* __restrict__ agg)
{
    const int t = blockIdx.x * 256 + threadIdx.x;
    const int node = t >> 5;                 // grid exact: 5000*256/32 = 40000
    const int l32 = t & 31;                  // lane within node group
    const int head = l32 >> 3;               // 8 lanes per head
    const int cb = l32 * 4;                  // first of 4 bf16 channels
    const float ad = adst[node * 4 + head];
    const int beg = rowptr[node] + bsum[node >> 8];
    const int end = rowptr[node + 1] + bsum[(node + 1) >> 8];
    float acc0 = 0.f, acc1 = 0.f, acc2 = 0.f, acc3 = 0.f, den = 0.f;

    int i = beg;
    for (; i + 8 <= end; i += 8) {
        int s[8];
        float a[8];
        uint2 w[8];
#pragma unroll
        for (int j = 0; j < 8; ++j) s[j] = esrc[i + j];
#pragma unroll
        for (int j = 0; j < 8; ++j) a[j] = asrc[s[j] * 4 + head];
#pragma unroll
        for (int j = 0; j < 8; ++j)
            w[j] = *(const uint2*)&h1b[(size_t)s[j] * 128 + cb];
#pragma unroll
        for (int j = 0; j < 8; ++j) {
            float v = a[j] + ad; v = v > 0.f ? v : 0.2f * v;
            const float e = __expf(v);
            den += e;
            acc0 = fmaf(e, bf_lo(w[j].x), acc0);
            acc1 = fmaf(e, bf_hi(w[j].x), acc1);
            acc2 = fmaf(e, bf_lo(w[j].y), acc2);
            acc3 = fmaf(e, bf_hi(w[j].y), acc3);
        }
    }
    for (; i < end; ++i) {
        const int s = esrc[i];
        float av = asrc[s * 4 + head] + ad;
        av = av > 0.f ? av : 0.2f * av;
        const float ex = __expf(av);
        const uint2 w = *(const uint2*)&h1b[(size_t)s * 128 + cb];
        den += ex;
        acc0 = fmaf(ex, bf_lo(w.x), acc0);
        acc1 = fmaf(ex, bf_hi(w.x), acc1);
        acc2 = fmaf(ex, bf_lo(w.y), acc2);
        acc3 = fmaf(ex, bf_hi(w.y), acc3);
    }

    const float inv = 1.f / (den + 1e-16f);
    const float4 bv = *(const float4*)&b[cb];
    float o0 = acc0 * inv + bv.x;
    float o1 = acc1 * inv + bv.y;
    float o2 = acc2 * inv + bv.z;
    float o3 = acc3 * inv + bv.w;
    o0 = o0 > 0.f ? o0 : expm1f(o0);
    o1 = o1 > 0.f ? o1 : expm1f(o1);
    o2 = o2 > 0.f ? o2 : expm1f(o2);
    o3 = o3 > 0.f ? o3 : expm1f(o3);
    *(float4*)&agg[(size_t)node * 128 + cb] = make_float4(o0, o1, o2, o3);
}

// ===========================================================================
// GEMM2: h2 = hin @ W2  [40000x128 @ 128x32], fused attention coeffs (1 head)
// ===========================================================================
__global__ __launch_bounds__(256) void gemm2_kernel(
    const float* __restrict__ hin, const float* __restrict__ W,
    const float* __restrict__ a_src, const float* __restrict__ a_dst,
    float* __restrict__ h2, float* __restrict__ asrc, float* __restrict__ adst)
{
    __shared__ float Ws[128 * 32];   // 16 KB
    {
        const float4* Wg = (const float4*)W;
        float4* Wl = (float4*)Ws;
        for (int i = threadIdx.x; i < 128 * 32 / 4; i += 256) Wl[i] = Wg[i];
    }
    __syncthreads();
    const int row0 = blockIdx.x * 64;
    const int tx = threadIdx.x & 7;
    const int ty = threadIdx.x >> 3;

    float acc[2][4];
#pragma unroll
    for (int r = 0; r < 2; ++r)
#pragma unroll
        for (int c = 0; c < 4; ++c) acc[r][c] = 0.f;

    for (int k0 = 0; k0 < 128; k0 += 4) {
        float xv[2][4];
#pragma unroll
        for (int r = 0; r < 2; ++r) {
            float4 t = *(const float4*)&hin[(size_t)(row0 + ty * 2 + r) * 128 + k0];
            xv[r][0] = t.x; xv[r][1] = t.y; xv[r][2] = t.z; xv[r][3] = t.w;
        }
#pragma unroll
        for (int kk = 0; kk < 4; ++kk) {
            float4 w = *(const float4*)&Ws[(k0 + kk) * 32 + tx * 4];
            float wreg[4] = { w.x, w.y, w.z, w.w };
#pragma unroll
            for (int r = 0; r < 2; ++r)
#pragma unroll
                for (int c = 0; c < 4; ++c)
                    acc[r][c] = fmaf(xv[r][kk], wreg[c], acc[r][c]);
        }
    }

    float as[4], ad[4];
#pragma unroll
    for (int c = 0; c < 4; ++c) {
        as[c] = a_src[tx * 4 + c];
        ad[c] = a_dst[tx * 4 + c];
    }
#pragma unroll
    for (int r = 0; r < 2; ++r) {
        const int n = row0 + ty * 2 + r;
        *(float4*)&h2[(size_t)n * 32 + tx * 4] =
            make_float4(acc[r][0], acc[r][1], acc[r][2], acc[r][3]);
        float ps = 0.f, pd = 0.f;
#pragma unroll
        for (int c = 0; c < 4; ++c) {
            ps = fmaf(acc[r][c], as[c], ps);
            pd = fmaf(acc[r][c], ad[c], pd);
        }
        ps += __shfl_xor(ps, 1); ps += __shfl_xor(ps, 2); ps += __shfl_xor(ps, 4);
        pd += __shfl_xor(pd, 1); pd += __shfl_xor(pd, 2); pd += __shfl_xor(pd, 4);
        if ((threadIdx.x & 7) == 0) { asrc[n] = ps; adst[n] = pd; }
    }
}

// ===========================================================================
// Gather pass 2: 32 lanes per dst node, 8-deep pipeline; fused norm+bias+ELU.
// ===========================================================================
__global__ __launch_bounds__(256) void gather2_kernel(
    const int* __restrict__ rowptr, const int* __restrict__ bsum,
    const int* __restrict__ esrc,
    const float* __restrict__ asrc, const float* __restrict__ adst,
    const float* __restrict__ h2, const float* __restrict__ b,
    float* __restrict__ agg)
{
    const int t = blockIdx.x * 256 + threadIdx.x;
    const int node = t >> 5;
    const int c = t & 31;
    if (node >= N_NODES) return;
    const float ad = adst[node];
    const int beg = rowptr[node] + bsum[node >> 8];
    const int end = rowptr[node + 1] + bsum[(node + 1) >> 8];
    float acc = 0.f, den = 0.f;

    int i = beg;
    for (; i + 8 <= end; i += 8) {
        int s[8];
        float a[8], h[8];
#pragma unroll
        for (int j = 0; j < 8; ++j) s[j] = esrc[i + j];
#pragma unroll
        for (int j = 0; j < 8; ++j) a[j] = asrc[s[j]];
#pragma unroll
        for (int j = 0; j < 8; ++j) h[j] = h2[(size_t)s[j] * 32 + c];
#pragma unroll
        for (int j = 0; j < 8; ++j) {
            float v = a[j] + ad; v = v > 0.f ? v : 0.2f * v;
            const float e = __expf(v);
            den += e;
            acc = fmaf(e, h[j], acc);
        }
    }
    for (; i < end; ++i) {
        const int s = esrc[i];
        float av = asrc[s] + ad;
        av = av > 0.f ? av : 0.2f * av;
        const float ex = __expf(av);
        den += ex;
        acc = fmaf(ex, h2[(size_t)s * 32 + c], acc);
    }

    const float inv = 1.f / (den + 1e-16f);
    float o = acc * inv + b[c];
    o = o > 0.f ? o : expm1f(o);
    agg[(size_t)node * 32 + c] = o;
}

// ===========================================================================
// Output GEMM: out = h3 @ W_out + b_out  [40000x32 @ 32x112]
// ===========================================================================
__global__ __launch_bounds__(256) void out_gemm_kernel(
    const float* __restrict__ h3, const float* __restrict__ W,
    const float* __restrict__ b, float* __restrict__ out)
{
    __shared__ float Ws[32 * 112];   // 14 KB
    {
        const float4* Wg = (const float4*)W;
        float4* Wl = (float4*)Ws;
        for (int i = threadIdx.x; i < 32 * 112 / 4; i += 256) Wl[i] = Wg[i];
    }
    __syncthreads();
    const int row0 = blockIdx.x * 32;
    const int tc = threadIdx.x & 15;
    const int tr = threadIdx.x >> 4;

    float acc[2][7];
#pragma unroll
    for (int r = 0; r < 2; ++r)
#pragma unroll
        for (int c = 0; c < 7; ++c) acc[r][c] = 0.f;

    for (int k0 = 0; k0 < 32; k0 += 4) {
        float xv[2][4];
#pragma unroll
        for (int r = 0; r < 2; ++r) {
            float4 t = *(const float4*)&h3[(size_t)(row0 + tr * 2 + r) * 32 + k0];
            xv[r][0] = t.x; xv[r][1] = t.y; xv[r][2] = t.z; xv[r][3] = t.w;
        }
#pragma unroll
        for (int kk = 0; kk < 4; ++kk) {
            float wv[7];
#pragma unroll
            for (int c = 0; c < 7; ++c) wv[c] = Ws[(k0 + kk) * 112 + tc * 7 + c];
#pragma unroll
            for (int r = 0; r < 2; ++r)
#pragma unroll
                for (int c = 0; c < 7; ++c)
                    acc[r][c] = fmaf(xv[r][kk], wv[c], acc[r][c]);
        }
    }
#pragma unroll
    for (int r = 0; r < 2; ++r) {
        const int n = row0 + tr * 2 + r;
#pragma unroll
        for (int c = 0; c < 7; ++c)
            out[(size_t)n * 112 + tc * 7 + c] = acc[r][c] + b[tc * 7 + c];
    }
}

// ===========================================================================
extern "C" void kernel_launch(void* const* d_in, const int* in_sizes, int n_in,
                              void* d_out, int out_size, void* d_ws, size_t ws_size,
                              hipStream_t stream) {
    const float* x      = (const float*)d_in[0];
    const int*   eidx   = (const int*)d_in[1];
    const float* W1     = (const float*)d_in[2];
    const float* a_src1 = (const float*)d_in[3];
    const float* a_dst1 = (const float*)d_in[4];
    const float* b1     = (const float*)d_in[5];
    const float* W2     = (const float*)d_in[6];
    const float* a_src2 = (const float*)d_in[7];
    const float* a_dst2 = (const float*)d_in[8];
    const float* b2     = (const float*)d_in[9];
    const float* W_out  = (const float*)d_in[10];
    const float* b_out  = (const float*)d_in[11];
    float* out = (float*)d_out;

    // ---- workspace layout (~38 MB) ----
    int* rowptr = (int*)d_ws;                 // 40064 (uses [0..40000])
    int* cnt    = rowptr + 40064;             // 40064 histogram (init = 1)
    int* bsum   = cnt + 40064;                // 192 block sums (exclusive)
    int* rank   = bsum + 192;                 // 680000 per-edge bucket rank
    ushort* Wf  = (ushort*)(rank + 680000);   // 16384 bf16 (32 KB, frag-ordered W1)
    int* esrc   = (int*)(Wf + 16384);         // 680000 CSR edge sources
    ushort* h1b  = (ushort*)(esrc + 680000);  // 40000*128 bf16
    float* asrc1 = (float*)(h1b + 5120000);   // 40000*4
    float* adst1 = asrc1 + 160000;            // 40000*4
    float* agg1  = adst1 + 160000;            // 40000*128
    // after gather1, h1b region is dead -> layer-2 buffers overlay it
    float* h2    = (float*)h1b;               // 40000*32
    float* asrc2 = h2 + 1280000;              // 40000
    float* adst2 = asrc2 + 40000;             // 40000
    float* agg2  = adst2 + 40000;             // 40000*32

    // cnt=1 init (self-loops -> rank 0) + W1 -> bf16 fragment pack
    prep_kernel<<<48, 256, 0, stream>>>(W1, (int4*)cnt, Wf);

    // Layer-1 GEMM (MFMA) ∥ histogram-with-rank — independent block partitions
    gemm1_hist_kernel<<<G1_BLOCKS + HIST_BLOCKS, 256, 0, stream>>>(
        x, Wf, a_src1, a_dst1, h1b, asrc1, adst1, eidx, cnt, rank);

    // CSR scan
    scanA_kernel<<<SCAN_BLOCKS, 256, 0, stream>>>(cnt, rowptr, bsum);
    scanB_kernel<<<1, 256, 0, stream>>>(bsum);

    // Atomic-free bucket fill
    fill_kernel<<<(E_TOT + 255) / 256, 256, 0, stream>>>(
        eidx, rowptr, bsum, rank, esrc);

    // Layer 1 aggregate (2 nodes/wave, 16 rows in flight)
    gather1_kernel<<<5000, 256, 0, stream>>>(rowptr, bsum, esrc, asrc1, adst1,
                                             h1b, b1, agg1);

    // Layer 2
    gemm2_kernel<<<625, 256, 0, stream>>>(agg1, W2, a_src2, a_dst2, h2, asrc2, adst2);
    gather2_kernel<<<5000, 256, 0, stream>>>(rowptr, bsum, esrc, asrc2, adst2,
                                             h2, b2, agg2);

    // Output projection
    out_gemm_kernel<<<1250, 256, 0, stream>>>(agg2, W_out, b_out, out);
}